// Round 1
// baseline (24573.199 us; speedup 1.0000x reference)
//
#include <hip/hip_runtime.h>
#include <math.h>

// Problem constants (VanillaRNN: T=129, B=1024, I=512, H=2048, k=63)
constexpr int Bsz  = 1024;
constexpr int Isz  = 512;
constexpr int Hsz  = 2048;
constexpr int Tenc = 65;   // k+2 encoder steps
constexpr int Tdec = 64;   // k+1 decoder steps

// ---------------------------------------------------------------------------
// Register-tiled fp32 NT GEMM:  C[m][n] = act( bias1[n](+bias2[n]) +
//      sum_k A1[m][k]*W1[n][k] (K1)  +  sum_k A2[m][k]*W2[n][k] (K2) )
// A row-major MxK, W row-major NxK (both contiguous along K -> coalesced).
// BM,BN tile; BK k-step; TM,TN per-thread microtile; 256 threads.
// ---------------------------------------------------------------------------
template<int BM, int BN, int BK, int TM, int TN, bool TANH>
__global__ __launch_bounds__(256) void gemm_nt(
    const float* __restrict__ A1, const float* __restrict__ W1, int K1,
    const float* __restrict__ A2, const float* __restrict__ W2, int K2,
    const float* __restrict__ bias1, const float* __restrict__ bias2,
    float* __restrict__ C, int M, int N)
{
    // +4 pad: row stride 68 floats -> 16B-aligned rows, bank rotation (4k+m)%32
    __shared__ float As[BK][BM + 4];
    __shared__ float Ws[BK][BN + 4];

    const int tid = threadIdx.x;
    const int tr  = tid / (BN / TN);   // thread row group
    const int tc  = tid % (BN / TN);   // thread col group
    const int m0  = blockIdx.y * BM;
    const int n0  = blockIdx.x * BN;

    float acc[TM][TN];
#pragma unroll
    for (int i = 0; i < TM; ++i)
#pragma unroll
        for (int j = 0; j < TN; ++j) acc[i][j] = 0.f;

    for (int phase = 0; phase < 2; ++phase) {
        const float* __restrict__ A = phase ? A2 : A1;
        const float* __restrict__ W = phase ? W2 : W1;
        const int K = phase ? K2 : K1;
        if (K == 0 || A == nullptr) continue;

        for (int k0 = 0; k0 < K; k0 += BK) {
            // ---- stage A tile (BM x BK), store transposed As[k][m] ----
            constexpr int F4A = BM * BK / 4;       // float4 count
            constexpr int PTA = F4A / 256;
#pragma unroll
            for (int p = 0; p < PTA; ++p) {
                int f   = tid + p * 256;
                int row = f / (BK / 4);
                int k4  = (f % (BK / 4)) * 4;
                float4 v = *(const float4*)(A + (size_t)(m0 + row) * K + k0 + k4);
                As[k4 + 0][row] = v.x;
                As[k4 + 1][row] = v.y;
                As[k4 + 2][row] = v.z;
                As[k4 + 3][row] = v.w;
            }
            // ---- stage W tile (BN x BK), store transposed Ws[k][n] ----
            constexpr int F4W = BN * BK / 4;
            constexpr int PTW = F4W / 256;
#pragma unroll
            for (int p = 0; p < PTW; ++p) {
                int f   = tid + p * 256;
                int row = f / (BK / 4);
                int k4  = (f % (BK / 4)) * 4;
                float4 v = *(const float4*)(W + (size_t)(n0 + row) * K + k0 + k4);
                Ws[k4 + 0][row] = v.x;
                Ws[k4 + 1][row] = v.y;
                Ws[k4 + 2][row] = v.z;
                Ws[k4 + 3][row] = v.w;
            }
            __syncthreads();

#pragma unroll
            for (int kk = 0; kk < BK; ++kk) {
                float a[TM], w[TN];
#pragma unroll
                for (int i = 0; i < TM; ++i) a[i] = As[kk][tr * TM + i];
#pragma unroll
                for (int j = 0; j < TN; ++j) w[j] = Ws[kk][tc * TN + j];
#pragma unroll
                for (int i = 0; i < TM; ++i)
#pragma unroll
                    for (int j = 0; j < TN; ++j)
                        acc[i][j] = fmaf(a[i], w[j], acc[i][j]);
            }
            __syncthreads();
        }
    }

    // ---- epilogue: bias (+bias2), optional tanh, float4 store (TN==4) ----
    float bb[TN];
#pragma unroll
    for (int j = 0; j < TN; ++j) {
        int n = n0 + tc * TN + j;
        float b = bias1 ? bias1[n] : 0.f;
        if (bias2) b += bias2[n];
        bb[j] = b;
    }
#pragma unroll
    for (int i = 0; i < TM; ++i) {
        int m = m0 + tr * TM + i;
        float4 r;
        float* rp = &r.x;
#pragma unroll
        for (int j = 0; j < TN; ++j) {
            float v = acc[i][j] + bb[j];
            if (TANH) v = tanhf(v);
            rp[j] = v;
        }
        *(float4*)(C + (size_t)m * N + n0 + tc * TN) = r;
    }
}

// ---------------------------------------------------------------------------
// Per-row log_softmax over Isz=512 logits + argmax==2 flag.
// One block (256 threads) per batch row; each thread owns elems tid, tid+256.
// Tie-break: lowest index wins (matches jnp.argmax).
// ---------------------------------------------------------------------------
__global__ __launch_bounds__(256) void logsoftmax_z(
    const float* __restrict__ logits,   // Bsz x Isz
    float* __restrict__ out,            // Bsz x Isz  (slice of d_out)
    float* __restrict__ z)              // Bsz
{
    const int b   = blockIdx.x;
    const int tid = threadIdx.x;
    const float* row = logits + (size_t)b * Isz;

    float v0 = row[tid];
    float v1 = row[tid + 256];

    float mv; int mi;
    if (v0 >= v1) { mv = v0; mi = tid; } else { mv = v1; mi = tid + 256; }

    // butterfly max+argmax across the 64-lane wave
#pragma unroll
    for (int off = 32; off; off >>= 1) {
        float ov = __shfl_xor(mv, off);
        int   oi = __shfl_xor(mi, off);
        if (ov > mv || (ov == mv && oi < mi)) { mv = ov; mi = oi; }
    }
    __shared__ float smv[4];
    __shared__ int   smi[4];
    const int wid = tid >> 6, lane = tid & 63;
    if (lane == 0) { smv[wid] = mv; smi[wid] = mi; }
    __syncthreads();
    if (tid == 0) {
        for (int w = 1; w < 4; ++w)
            if (smv[w] > smv[0] || (smv[w] == smv[0] && smi[w] < smi[0])) {
                smv[0] = smv[w]; smi[0] = smi[w];
            }
    }
    __syncthreads();
    mv = smv[0]; mi = smi[0];

    // sum of exp(x - max)
    float s = expf(v0 - mv) + expf(v1 - mv);
#pragma unroll
    for (int off = 32; off; off >>= 1) s += __shfl_xor(s, off);
    __shared__ float ssum[4];
    if (lane == 0) ssum[wid] = s;
    __syncthreads();
    if (tid == 0) ssum[0] = ssum[0] + ssum[1] + ssum[2] + ssum[3];
    __syncthreads();
    const float ls = logf(ssum[0]);

    float* orow = out + (size_t)b * Isz;
    orow[tid]       = v0 - mv - ls;
    orow[tid + 256] = v1 - mv - ls;
    if (tid == 0) z[b] = (mi == 2) ? 1.f : 0.f;
}

// ---------------------------------------------------------------------------
// Done-latch blend: for each batch b, done_t = max_{t'<=t} z_{t'}; rows with
// done==1 become the one-hot `begin` (1 at index 0).
// ---------------------------------------------------------------------------
__global__ __launch_bounds__(64) void blend_done(
    const float* __restrict__ z,   // Tdec x Bsz
    float* __restrict__ out)       // Tdec x Bsz x Isz
{
    const int b   = blockIdx.x;
    const int tid = threadIdx.x;
    float done = 0.f;
    for (int t = 0; t < Tdec; ++t) {
        done = fmaxf(done, z[(size_t)t * Bsz + b]);
        if (done > 0.5f) {
            float* row = out + ((size_t)t * Bsz + b) * Isz;
            for (int j = tid; j < Isz; j += 64) row[j] = (j == 0) ? 1.f : 0.f;
        }
    }
}

// ---------------------------------------------------------------------------
extern "C" void kernel_launch(void* const* d_in, const int* in_sizes, int n_in,
                              void* d_out, int out_size, void* d_ws, size_t ws_size,
                              hipStream_t stream)
{
    const float* x    = (const float*)d_in[0];
    const float* eWih = (const float*)d_in[1];
    const float* eWhh = (const float*)d_in[2];
    const float* ebih = (const float*)d_in[3];
    const float* ebhh = (const float*)d_in[4];
    // d_in[5] = dec_Wih (unused by the reference decoder step)
    const float* dWhh = (const float*)d_in[6];
    const float* dbih = (const float*)d_in[7];
    const float* dbhh = (const float*)d_in[8];
    const float* roW  = (const float*)d_in[9];
    const float* rob  = (const float*)d_in[10];
    float* out = (float*)d_out;

    char* ws = (char*)d_ws;
    const size_t hbytes = (size_t)Bsz * Hsz * sizeof(float);
    float* h[2]   = { (float*)ws, (float*)(ws + hbytes) };
    float* logits = (float*)(ws + 2 * hbytes);
    float* z      = (float*)(ws + 2 * hbytes + (size_t)Bsz * Isz * sizeof(float));

    hipMemsetAsync(h[0], 0, hbytes, stream);

    const dim3 blk(256);
    const dim3 grid_h(Hsz / 64, Bsz / 64);    // 32 x 16 = 512 blocks
    const dim3 grid_ro(Isz / 64, Bsz / 32);   //  8 x 32 = 256 blocks

    int cur = 0;
    // ---- encoder: 65 steps of h = tanh(x_t@Wih^T + bih + h@Whh^T + bhh) ----
    for (int t = 0; t < Tenc; ++t) {
        gemm_nt<64, 64, 32, 4, 4, true><<<grid_h, blk, 0, stream>>>(
            x + (size_t)t * Bsz * Isz, eWih, Isz,
            h[cur], eWhh, Hsz,
            ebih, ebhh, h[cur ^ 1], Bsz, Hsz);
        cur ^= 1;
    }
    // ---- decoder: 64 steps ----
    for (int t = 0; t < Tdec; ++t) {
        gemm_nt<64, 64, 32, 4, 4, true><<<grid_h, blk, 0, stream>>>(
            nullptr, nullptr, 0,
            h[cur], dWhh, Hsz,
            dbih, dbhh, h[cur ^ 1], Bsz, Hsz);
        cur ^= 1;
        gemm_nt<32, 64, 32, 2, 4, false><<<grid_ro, blk, 0, stream>>>(
            nullptr, nullptr, 0,
            h[cur], roW, Hsz,
            rob, nullptr, logits, Bsz, Isz);
        logsoftmax_z<<<dim3(Bsz), dim3(256), 0, stream>>>(
            logits, out + (size_t)t * Bsz * Isz, z + (size_t)t * Bsz);
    }
    blend_done<<<dim3(Bsz), dim3(64), 0, stream>>>(z, out);
}

// Round 2
// 14396.198 us; speedup vs baseline: 1.7069x; 1.7069x over previous
//
#include <hip/hip_runtime.h>
#include <math.h>

// Problem constants (VanillaRNN: T=129, B=1024, I=512, H=2048, k=63)
constexpr int Bsz  = 1024;
constexpr int Isz  = 512;
constexpr int Hsz  = 2048;
constexpr int Tenc = 65;   // k+2 encoder steps
constexpr int Tdec = 64;   // k+1 decoder steps

typedef _Float16 half8 __attribute__((ext_vector_type(8)));
typedef float    f32x4 __attribute__((ext_vector_type(4)));
typedef unsigned int uint;
typedef unsigned short ushort;

// ---- packed split-fp16 pair: lo = f16(v), hi = f16((v - lo) * 4096) ----
__device__ inline uint pack_split(float v) {
    _Float16 a0 = (_Float16)v;
    float r = (v - (float)a0) * 4096.f;
    _Float16 a1 = (_Float16)r;
    return ((uint)__builtin_bit_cast(ushort, a1) << 16) | __builtin_bit_cast(ushort, a0);
}

struct U8 { uint4 a, b; };
__device__ inline U8 ld8(const uint* __restrict__ p) {
    U8 r; r.a = *(const uint4*)p; r.b = *(const uint4*)(p + 4); return r;
}

// 8 fp32 -> (lo8, hi8) split halves
__device__ inline void split8(const U8& v, half8& lo, half8& hi) {
    union { uint4 u; float f[4]; } A, B;
    A.u = v.a; B.u = v.b;
    float x[8] = {A.f[0], A.f[1], A.f[2], A.f[3], B.f[0], B.f[1], B.f[2], B.f[3]};
#pragma unroll
    for (int e = 0; e < 8; ++e) {
        _Float16 a0 = (_Float16)x[e];
        float r = (x[e] - (float)a0) * 4096.f;
        lo[e] = a0; hi[e] = (_Float16)r;
    }
}

// 8 packed uint32 -> (lo8, hi8) via byte-perm
__device__ inline void unpack8(const U8& v, half8& lo, half8& hi) {
    union { uint u[4]; half8 h; } L, H;
    uint w[8] = {v.a.x, v.a.y, v.a.z, v.a.w, v.b.x, v.b.y, v.b.z, v.b.w};
#pragma unroll
    for (int q = 0; q < 4; ++q) {
        L.u[q] = __builtin_amdgcn_perm(w[2*q+1], w[2*q], 0x05040100u);
        H.u[q] = __builtin_amdgcn_perm(w[2*q+1], w[2*q], 0x07060302u);
    }
    lo = L.h; hi = H.h;
}

// XOR-swizzled LDS index (16B units): window of 4 kq per row, 2-way max conflict
#define SWZ(row, kk) (((row) * 4 + ((kk) ^ (((row) >> 1) & 3))) * 8)

// ---------------------------------------------------------------------------
// Split-fp16 MFMA GEMM:  C[m][n] = act( bias1[n](+bias2[n]) +
//     sum_k A1[m][k]*B1[n][k]  (K1, A1 fp32, staged-split)
//   + sum_k A2[m][k]*B2[n][k]  (K2, A2 packed-split uint32) )
// B1/B2 are packed-split uint32 (b_f32=false) or fp32 (b_f32=true).
// 16x16x32_f16 MFMA; emulated fp32 via (a0 + a1/4096)*(b0 + b1/4096).
// ---------------------------------------------------------------------------
template<int BM, int BN, int WR, int WC, int MP, int NP, bool TANH, bool PACKOUT>
__global__ __launch_bounds__(WR*WC*64) void gemm_sp(
    const float* __restrict__ A1, int K1, const void* __restrict__ B1,
    const uint*  __restrict__ A2, int K2, const void* __restrict__ B2,
    int b_f32,
    const float* __restrict__ bias1, const float* __restrict__ bias2,
    void* __restrict__ C, int M, int N)
{
    constexpr int NT  = WR * WC * 64;
    constexpr int AUP = BM * 4 / NT;   // 8-elem units per thread (A)
    constexpr int BUP = BN * 4 / NT;   // 8-elem units per thread (B)

    __shared__ __align__(16) _Float16 As0[BM*32], As1[BM*32];
    __shared__ __align__(16) _Float16 Bs0[BN*32], Bs1[BN*32];

    const int tid  = threadIdx.x;
    const int wid  = tid >> 6, lane = tid & 63;
    const int wrow = wid / WC, wcol = wid % WC;
    const int kq   = lane >> 4, lr = lane & 15;
    const int m0   = blockIdx.y * BM;
    const int n0   = blockIdx.x * BN;

    // staging unit coords + LDS write ptrs (fixed across K loop)
    int aum[AUP], auk[AUP]; _Float16 *aw0[AUP], *aw1[AUP];
#pragma unroll
    for (int p = 0; p < AUP; ++p) {
        int u = tid + p * NT; aum[p] = u >> 2; auk[p] = u & 3;
        int o = SWZ(aum[p], auk[p]); aw0[p] = As0 + o; aw1[p] = As1 + o;
    }
    int bun[BUP], buk[BUP]; _Float16 *bw0[BUP], *bw1[BUP];
#pragma unroll
    for (int p = 0; p < BUP; ++p) {
        int u = tid + p * NT; bun[p] = u >> 2; buk[p] = u & 3;
        int o = SWZ(bun[p], buk[p]); bw0[p] = Bs0 + o; bw1[p] = Bs1 + o;
    }
    // fragment read offsets (fixed)
    int aoff[MP], boff[NP];
#pragma unroll
    for (int i = 0; i < MP; ++i) { int m = wrow*(MP*16) + i*16 + lr; aoff[i] = SWZ(m, kq); }
#pragma unroll
    for (int j = 0; j < NP; ++j) { int n = wcol*(NP*16) + j*16 + lr; boff[j] = SWZ(n, kq); }

    f32x4 acc0[MP][NP] = {}; f32x4 acc1[MP][NP] = {};

    const int R = (K1 + K2) / 32;

    auto issue = [&](int rd, U8* aR, U8* bR) {
        const bool ph1 = (rd * 32) < K1;
        const int  kl  = ph1 ? rd * 32 : rd * 32 - K1;
        const int  Ka  = ph1 ? K1 : K2;
        const uint* Ap = ph1 ? (const uint*)A1 : A2;
        const uint* Bp = (const uint*)(ph1 ? B1 : B2);
#pragma unroll
        for (int p = 0; p < AUP; ++p)
            aR[p] = ld8(Ap + (size_t)(m0 + aum[p]) * Ka + kl + auk[p] * 8);
#pragma unroll
        for (int p = 0; p < BUP; ++p)
            bR[p] = ld8(Bp + (size_t)(n0 + bun[p]) * Ka + kl + buk[p] * 8);
    };

    auto stage = [&](U8* aR, U8* bR, bool aF32) {
#pragma unroll
        for (int p = 0; p < AUP; ++p) {
            half8 lo, hi;
            if (aF32) split8(aR[p], lo, hi); else unpack8(aR[p], lo, hi);
            *(half8*)aw0[p] = lo; *(half8*)aw1[p] = hi;
        }
#pragma unroll
        for (int p = 0; p < BUP; ++p) {
            half8 lo, hi;
            if (b_f32) split8(bR[p], lo, hi); else unpack8(bR[p], lo, hi);
            *(half8*)bw0[p] = lo; *(half8*)bw1[p] = hi;
        }
    };

    auto compute = [&]() {
        half8 a0[MP], a1[MP], b0[NP], b1[NP];
#pragma unroll
        for (int i = 0; i < MP; ++i) {
            a0[i] = *(const half8*)(As0 + aoff[i]);
            a1[i] = *(const half8*)(As1 + aoff[i]);
        }
#pragma unroll
        for (int j = 0; j < NP; ++j) {
            b0[j] = *(const half8*)(Bs0 + boff[j]);
            b1[j] = *(const half8*)(Bs1 + boff[j]);
        }
#pragma unroll
        for (int i = 0; i < MP; ++i)
#pragma unroll
            for (int j = 0; j < NP; ++j) {
                acc0[i][j] = __builtin_amdgcn_mfma_f32_16x16x32_f16(a0[i], b0[j], acc0[i][j], 0, 0, 0);
                acc1[i][j] = __builtin_amdgcn_mfma_f32_16x16x32_f16(a1[i], b0[j], acc1[i][j], 0, 0, 0);
                acc1[i][j] = __builtin_amdgcn_mfma_f32_16x16x32_f16(a0[i], b1[j], acc1[i][j], 0, 0, 0);
            }
    };

    // main loop, 2-step unrolled double register buffer, prefetch-1
    U8 aA[AUP], bA[BUP], aB[AUP], bB[BUP];
    issue(0, aA, bA);
    for (int rd = 0; rd < R; rd += 2) {
        if (rd + 1 < R) issue(rd + 1, aB, bB);
        stage(aA, bA, (rd * 32) < K1);
        __syncthreads();
        compute();
        __syncthreads();
        if (rd + 1 < R) {
            if (rd + 2 < R) issue(rd + 2, aA, bA);
            stage(aB, bB, ((rd + 1) * 32) < K1);
            __syncthreads();
            compute();
            __syncthreads();
        }
    }

    // epilogue: combine scales, bias, tanh, store
#pragma unroll
    for (int j = 0; j < NP; ++j) {
        const int n = n0 + wcol*(NP*16) + j*16 + lr;
        float bb = bias1 ? bias1[n] : 0.f;
        if (bias2) bb += bias2[n];
#pragma unroll
        for (int i = 0; i < MP; ++i) {
            const int mb = m0 + wrow*(MP*16) + i*16 + kq*4;
#pragma unroll
            for (int r = 0; r < 4; ++r) {
                float val = acc0[i][j][r] + 0x1p-12f * acc1[i][j][r] + bb;
                if (TANH) val = tanhf(val);
                if (PACKOUT)
                    ((uint*)C)[(size_t)(mb + r) * N + n] = pack_split(val);
                else
                    ((float*)C)[(size_t)(mb + r) * N + n] = val;
            }
        }
    }
}

// ---------------------------------------------------------------------------
// Weight prep: fp32 -> packed split pair
// ---------------------------------------------------------------------------
__global__ __launch_bounds__(256) void split_pack_k(
    const float* __restrict__ s, uint* __restrict__ d, int n)
{
    for (int i = blockIdx.x * 256 + threadIdx.x; i < n; i += gridDim.x * 256)
        d[i] = pack_split(s[i]);
}

// ---------------------------------------------------------------------------
// Per-row log_softmax over Isz=512 logits + argmax==2 flag.
// ---------------------------------------------------------------------------
__global__ __launch_bounds__(256) void logsoftmax_z(
    const float* __restrict__ logits, float* __restrict__ out, float* __restrict__ z)
{
    const int b   = blockIdx.x;
    const int tid = threadIdx.x;
    const float* row = logits + (size_t)b * Isz;

    float v0 = row[tid];
    float v1 = row[tid + 256];

    float mv; int mi;
    if (v0 >= v1) { mv = v0; mi = tid; } else { mv = v1; mi = tid + 256; }
#pragma unroll
    for (int off = 32; off; off >>= 1) {
        float ov = __shfl_xor(mv, off);
        int   oi = __shfl_xor(mi, off);
        if (ov > mv || (ov == mv && oi < mi)) { mv = ov; mi = oi; }
    }
    __shared__ float smv[4];
    __shared__ int   smi[4];
    const int wid = tid >> 6, lane = tid & 63;
    if (lane == 0) { smv[wid] = mv; smi[wid] = mi; }
    __syncthreads();
    if (tid == 0) {
        for (int w = 1; w < 4; ++w)
            if (smv[w] > smv[0] || (smv[w] == smv[0] && smi[w] < smi[0])) {
                smv[0] = smv[w]; smi[0] = smi[w];
            }
    }
    __syncthreads();
    mv = smv[0]; mi = smi[0];

    float s = expf(v0 - mv) + expf(v1 - mv);
#pragma unroll
    for (int off = 32; off; off >>= 1) s += __shfl_xor(s, off);
    __shared__ float ssum[4];
    if (lane == 0) ssum[wid] = s;
    __syncthreads();
    if (tid == 0) ssum[0] = ssum[0] + ssum[1] + ssum[2] + ssum[3];
    __syncthreads();
    const float ls = logf(ssum[0]);

    float* orow = out + (size_t)b * Isz;
    orow[tid]       = v0 - mv - ls;
    orow[tid + 256] = v1 - mv - ls;
    if (tid == 0) z[b] = (mi == 2) ? 1.f : 0.f;
}

// ---------------------------------------------------------------------------
__global__ __launch_bounds__(64) void blend_done(
    const float* __restrict__ z, float* __restrict__ out)
{
    const int b   = blockIdx.x;
    const int tid = threadIdx.x;
    float done = 0.f;
    for (int t = 0; t < Tdec; ++t) {
        done = fmaxf(done, z[(size_t)t * Bsz + b]);
        if (done > 0.5f) {
            float* row = out + ((size_t)t * Bsz + b) * Isz;
            for (int j = tid; j < Isz; j += 64) row[j] = (j == 0) ? 1.f : 0.f;
        }
    }
}

// ---------------------------------------------------------------------------
extern "C" void kernel_launch(void* const* d_in, const int* in_sizes, int n_in,
                              void* d_out, int out_size, void* d_ws, size_t ws_size,
                              hipStream_t stream)
{
    const float* x    = (const float*)d_in[0];
    const float* eWih = (const float*)d_in[1];
    const float* eWhh = (const float*)d_in[2];
    const float* ebih = (const float*)d_in[3];
    const float* ebhh = (const float*)d_in[4];
    const float* dWhh = (const float*)d_in[6];
    const float* dbih = (const float*)d_in[7];
    const float* dbhh = (const float*)d_in[8];
    const float* roW  = (const float*)d_in[9];
    const float* rob  = (const float*)d_in[10];
    float* out = (float*)d_out;

    // workspace layout
    const size_t sz_eWih = (size_t)Hsz * Isz * 4;   //  4 MB
    const size_t sz_eWhh = (size_t)Hsz * Hsz * 4;   // 16 MB
    const size_t sz_dWhh = sz_eWhh;                 // 16 MB
    const size_t sz_roW  = (size_t)Isz * Hsz * 4;   //  4 MB
    const size_t sz_h    = (size_t)Bsz * Hsz * 4;   //  8 MB (packed)
    const size_t sz_lg   = (size_t)Bsz * Isz * 4;   //  2 MB
    const size_t sz_z    = (size_t)Tdec * Bsz * 4;

    const size_t need_prep = sz_eWih + sz_eWhh + sz_dWhh + sz_roW + 2*sz_h + sz_lg + sz_z;
    const bool prep = ws_size >= need_prep;

    char* ws = (char*)d_ws;
    uint *pWih = nullptr, *pWhh = nullptr, *pdWhh = nullptr, *proW = nullptr;
    size_t off = 0;
    if (prep) {
        pWih  = (uint*)(ws + off); off += sz_eWih;
        pWhh  = (uint*)(ws + off); off += sz_eWhh;
        pdWhh = (uint*)(ws + off); off += sz_dWhh;
        proW  = (uint*)(ws + off); off += sz_roW;
    }
    uint*  hA     = (uint*)(ws + off); off += sz_h;
    uint*  hB     = (uint*)(ws + off); off += sz_h;
    float* logits = (float*)(ws + off); off += sz_lg;
    float* zbuf   = (float*)(ws + off);

    if (prep) {
        split_pack_k<<<dim3(1024), dim3(256), 0, stream>>>(eWih, pWih,  Hsz*Isz);
        split_pack_k<<<dim3(2048), dim3(256), 0, stream>>>(eWhh, pWhh,  Hsz*Hsz);
        split_pack_k<<<dim3(2048), dim3(256), 0, stream>>>(dWhh, pdWhh, Hsz*Hsz);
        split_pack_k<<<dim3(1024), dim3(256), 0, stream>>>(roW,  proW,  Isz*Hsz);
    }
    const int bF32 = prep ? 0 : 1;
    const void* B_eWih = prep ? (const void*)pWih  : (const void*)eWih;
    const void* B_eWhh = prep ? (const void*)pWhh  : (const void*)eWhh;
    const void* B_dWhh = prep ? (const void*)pdWhh : (const void*)dWhh;
    const void* B_roW  = prep ? (const void*)proW  : (const void*)roW;

    hipMemsetAsync(hA, 0, sz_h, stream);   // h0 = 0 (packed zero == 0)

    uint* h[2] = { hA, hB };
    const dim3 blk(256);
    const dim3 grid_h(Hsz / 128, Bsz / 64);   // (16,16) = 256 blocks
    const dim3 grid_ro(Isz / 64, Bsz / 64);   // (8,16)  = 128 blocks

    int cur = 0;
    // ---- encoder: 65 steps of h = tanh(x_t@Wih^T + bih + h@Whh^T + bhh) ----
    for (int t = 0; t < Tenc; ++t) {
        gemm_sp<64, 128, 2, 2, 2, 4, true, true><<<grid_h, blk, 0, stream>>>(
            x + (size_t)t * Bsz * Isz, Isz, B_eWih,
            h[cur], Hsz, B_eWhh, bF32,
            ebih, ebhh, h[cur ^ 1], Bsz, Hsz);
        cur ^= 1;
    }
    // ---- decoder: 64 steps ----
    for (int t = 0; t < Tdec; ++t) {
        gemm_sp<64, 128, 2, 2, 2, 4, true, true><<<grid_h, blk, 0, stream>>>(
            nullptr, 0, nullptr,
            h[cur], Hsz, B_dWhh, bF32,
            dbih, dbhh, h[cur ^ 1], Bsz, Hsz);
        cur ^= 1;
        gemm_sp<64, 64, 2, 2, 2, 2, false, false><<<grid_ro, blk, 0, stream>>>(
            nullptr, 0, nullptr,
            h[cur], Hsz, B_roW, bF32,
            rob, nullptr, logits, Bsz, Isz);
        logsoftmax_z<<<dim3(Bsz), dim3(256), 0, stream>>>(
            logits, out + (size_t)t * Bsz * Isz, zbuf + (size_t)t * Bsz);
    }
    blend_done<<<dim3(Bsz), dim3(64), 0, stream>>>(zbuf, out);
}

// Round 3
// 12345.279 us; speedup vs baseline: 1.9905x; 1.1661x over previous
//
#include <hip/hip_runtime.h>
#include <math.h>

// Problem constants (VanillaRNN: T=129, B=1024, I=512, H=2048, k=63)
constexpr int Bsz  = 1024;
constexpr int Isz  = 512;
constexpr int Hsz  = 2048;
constexpr int Tenc = 65;   // k+2 encoder steps
constexpr int Tdec = 64;   // k+1 decoder steps

typedef _Float16 half8 __attribute__((ext_vector_type(8)));
typedef float    f32x4 __attribute__((ext_vector_type(4)));
typedef unsigned int uint;
typedef unsigned short ushort;

// ---- packed split-fp16 pair: lo = f16(v), hi = f16((v - lo) * 4096) ----
__device__ inline uint pack_split(float v) {
    _Float16 a0 = (_Float16)v;
    float r = (v - (float)a0) * 4096.f;
    _Float16 a1 = (_Float16)r;
    return ((uint)__builtin_bit_cast(ushort, a1) << 16) | __builtin_bit_cast(ushort, a0);
}

struct U8 { uint4 a, b; };
__device__ inline U8 ld8(const uint* __restrict__ p) {
    U8 r; r.a = *(const uint4*)p; r.b = *(const uint4*)(p + 4); return r;
}

// 8 fp32 -> (lo8, hi8) split halves (fallback path)
__device__ inline void split8(const U8& v, half8& lo, half8& hi) {
    union { uint4 u; float f[4]; } A, B;
    A.u = v.a; B.u = v.b;
    float x[8] = {A.f[0], A.f[1], A.f[2], A.f[3], B.f[0], B.f[1], B.f[2], B.f[3]};
#pragma unroll
    for (int e = 0; e < 8; ++e) {
        _Float16 a0 = (_Float16)x[e];
        float r = (x[e] - (float)a0) * 4096.f;
        lo[e] = a0; hi[e] = (_Float16)r;
    }
}

// 8 packed uint32 -> (lo8, hi8) via byte-perm
__device__ inline void unpack8(const U8& v, half8& lo, half8& hi) {
    union { uint u[4]; half8 h; } L, H;
    uint w[8] = {v.a.x, v.a.y, v.a.z, v.a.w, v.b.x, v.b.y, v.b.z, v.b.w};
#pragma unroll
    for (int q = 0; q < 4; ++q) {
        L.u[q] = __builtin_amdgcn_perm(w[2*q+1], w[2*q], 0x05040100u);
        H.u[q] = __builtin_amdgcn_perm(w[2*q+1], w[2*q], 0x07060302u);
    }
    lo = L.h; hi = H.h;
}

// async global(16B) -> LDS, per-lane global src, wave-uniform LDS base
__device__ __forceinline__ void gll16(const uint* g, uint* l) {
    __builtin_amdgcn_global_load_lds(
        (const __attribute__((address_space(1))) void*)(uintptr_t)g,
        (__attribute__((address_space(3))) void*)(unsigned int)(uintptr_t)l,
        16, 0, 0);
}

// ===========================================================================
// FAST PATH: all-packed split-f16 GEMM, global_load_lds staging, depth-2
// pipeline, counted vmcnt. BM=BN=128, 4 waves (2x2), wave-tile 64x64.
// C = act(bias1+bias2 + A1*B1^T (K1) + A2*B2^T (K2)); all matrices packed
// uint32 (lo f16 | hi f16<<16), row-major [rows][K].
// LDS layout: packed uint, row*128B, 16B-unit u stored at (u ^ (row&7)).
// ===========================================================================
template<bool TANH, bool PARTIAL>
__global__ __launch_bounds__(256, 1) void gemm_pk(
    const uint* __restrict__ A1, int K1, const uint* __restrict__ B1,
    const uint* __restrict__ A2, int K2, const uint* __restrict__ B2,
    const float* __restrict__ bias1, const float* __restrict__ bias2,
    void* __restrict__ C, int M, int N, int GM, int GN, int KS)
{
    __shared__ uint ldsA[3 * 128 * 32];
    __shared__ uint ldsB[3 * 128 * 32];

    const int tid  = threadIdx.x;
    const int wid  = tid >> 6, lane = tid & 63;
    const int wr   = wid >> 1, wc = wid & 1;
    const int kq   = lane >> 4, lr = lane & 15;

    // ---- XCD-stable block decode: n-strip pinned to an XCD ----
    const int L = blockIdx.x, xcd = L & 7, g = L >> 3;
    int n_b, m_b, ks;
    const int spx = GN >> 3;
    if (spx > 0) {
        n_b = xcd * spx + (g % spx);
        int r = g / spx; m_b = r % GM; ks = r / GM;
    } else {
        const int xpn = 8 / GN;
        n_b = xcd / xpn;
        int r = g * xpn + (xcd % xpn); m_b = r % GM; ks = r / GM;
    }
    const int m0 = m_b * 128, n0 = n_b * 128;

    // ---- staging source offsets (uint elements), per issue q ----
    int offA1[4], offA2[4], offB1[4], offB2[4];
#pragma unroll
    for (int q = 0; q < 4; ++q) {
        int U = q * 256 + tid, row = U >> 3, us = U & 7;
        int u = us ^ (row & 7);                   // inverse read-swizzle on SOURCE
        offA1[q] = (m0 + row) * K1 + u * 4;
        offA2[q] = (m0 + row) * K2 + u * 4;
        offB1[q] = (n0 + row) * K1 + u * 4;
        offB2[q] = (n0 + row) * K2 + u * 4;
    }
    const int ldsbase = (tid & ~63) * 4;          // wave-uniform, uints

    const int R1 = K1 / 32;
    const int R  = (K1 + K2) / 32;
    const int nr = R / KS;
    const int r0 = ks * nr;

    auto STAGE = [&](int r, int bi) {
        uint* Ab = ldsA + bi * 4096;
        uint* Bb = ldsB + bi * 4096;
        const bool ph1 = r < R1;
        const int kl = (ph1 ? r : r - R1) * 32;
        const uint* As = ph1 ? A1 : A2;
        const uint* Bs = ph1 ? B1 : B2;
#pragma unroll
        for (int q = 0; q < 4; ++q) {
            gll16(As + (ph1 ? offA1[q] : offA2[q]) + kl, Ab + q * 1024 + ldsbase);
            gll16(Bs + (ph1 ? offB1[q] : offB2[q]) + kl, Bb + q * 1024 + ldsbase);
        }
    };

    f32x4 acc0[4][4] = {}; f32x4 acc1[4][4] = {};

    auto FRAG = [&](const uint* buf, int row, half8& lo, half8& hi) {
        const int b = row * 8, s = row & 7;
        U8 v;
        v.a = *(const uint4*)(buf + (b + ((2 * kq)     ^ s)) * 4);
        v.b = *(const uint4*)(buf + (b + ((2 * kq + 1) ^ s)) * 4);
        unpack8(v, lo, hi);
    };

    auto COMPUTE = [&](int bi) {
        const uint* Ab = ldsA + bi * 4096;
        const uint* Bb = ldsB + bi * 4096;
        half8 a0[4], a1[4];
#pragma unroll
        for (int i = 0; i < 4; ++i) FRAG(Ab, wr * 64 + i * 16 + lr, a0[i], a1[i]);
#pragma unroll
        for (int j = 0; j < 4; ++j) {
            half8 b0, b1;
            FRAG(Bb, wc * 64 + j * 16 + lr, b0, b1);
#pragma unroll
            for (int i = 0; i < 4; ++i) {
                acc0[i][j] = __builtin_amdgcn_mfma_f32_16x16x32_f16(a0[i], b0, acc0[i][j], 0, 0, 0);
                acc1[i][j] = __builtin_amdgcn_mfma_f32_16x16x32_f16(a1[i], b0, acc1[i][j], 0, 0, 0);
                acc1[i][j] = __builtin_amdgcn_mfma_f32_16x16x32_f16(a0[i], b1, acc1[i][j], 0, 0, 0);
            }
        }
    };

    // ---- prologue: stage rounds r0, r0+1 ----
    STAGE(r0, 0);
    STAGE(r0 + 1, 1);
    __builtin_amdgcn_sched_barrier(0);
    asm volatile("s_waitcnt vmcnt(8)" ::: "memory");
    __builtin_amdgcn_s_barrier();
    __builtin_amdgcn_sched_barrier(0);

    // ---- main loop ----
    int bi = 0;
    for (int t = 0; t < nr; ++t) {
        const bool more = (t + 2 < nr);
        if (more) {
            int b2 = bi + 2; if (b2 >= 3) b2 -= 3;
            STAGE(r0 + t + 2, b2);
        }
        COMPUTE(bi);
        __builtin_amdgcn_sched_barrier(0);
        if (more) asm volatile("s_waitcnt vmcnt(8)" ::: "memory");
        else      asm volatile("s_waitcnt vmcnt(0)" ::: "memory");
        __builtin_amdgcn_s_barrier();
        __builtin_amdgcn_sched_barrier(0);
        if (++bi == 3) bi = 0;
    }

    // ---- epilogue ----
#pragma unroll
    for (int j = 0; j < 4; ++j) {
        const int n = n0 + wc * 64 + j * 16 + lr;
        float bb = 0.f;
        if (!PARTIAL) {
            bb = bias1 ? bias1[n] : 0.f;
            if (bias2) bb += bias2[n];
        }
#pragma unroll
        for (int i = 0; i < 4; ++i) {
            const int mb = m0 + wr * 64 + i * 16 + kq * 4;
#pragma unroll
            for (int r = 0; r < 4; ++r) {
                float val = acc0[i][j][r] + 0x1p-12f * acc1[i][j][r] + bb;
                if (PARTIAL) {
                    ((float*)C)[(size_t)ks * M * N + (size_t)(mb + r) * N + n] = val;
                } else {
                    if (TANH) val = tanhf(val);
                    ((uint*)C)[(size_t)(mb + r) * N + n] = pack_split(val);
                }
            }
        }
    }
}

// ===========================================================================
// FALLBACK PATH (round-2 kernel, reg-staged; handles fp32 B when ws tiny)
// ===========================================================================
#define SWZ(row, kk) (((row) * 4 + ((kk) ^ (((row) >> 1) & 3))) * 8)

template<int BM, int BN, int WR, int WC, int MP, int NP, bool TANH, bool PACKOUT>
__global__ __launch_bounds__(WR*WC*64) void gemm_sp(
    const float* __restrict__ A1, int K1, const void* __restrict__ B1,
    const uint*  __restrict__ A2, int K2, const void* __restrict__ B2,
    int b_f32,
    const float* __restrict__ bias1, const float* __restrict__ bias2,
    void* __restrict__ C, int M, int N)
{
    constexpr int NT  = WR * WC * 64;
    constexpr int AUP = BM * 4 / NT;
    constexpr int BUP = BN * 4 / NT;

    __shared__ __align__(16) _Float16 As0[BM*32], As1[BM*32];
    __shared__ __align__(16) _Float16 Bs0[BN*32], Bs1[BN*32];

    const int tid  = threadIdx.x;
    const int wid  = tid >> 6, lane = tid & 63;
    const int wrow = wid / WC, wcol = wid % WC;
    const int kq   = lane >> 4, lr = lane & 15;
    const int m0   = blockIdx.y * BM;
    const int n0   = blockIdx.x * BN;

    int aum[AUP], auk[AUP]; _Float16 *aw0[AUP], *aw1[AUP];
#pragma unroll
    for (int p = 0; p < AUP; ++p) {
        int u = tid + p * NT; aum[p] = u >> 2; auk[p] = u & 3;
        int o = SWZ(aum[p], auk[p]); aw0[p] = As0 + o; aw1[p] = As1 + o;
    }
    int bun[BUP], buk[BUP]; _Float16 *bw0[BUP], *bw1[BUP];
#pragma unroll
    for (int p = 0; p < BUP; ++p) {
        int u = tid + p * NT; bun[p] = u >> 2; buk[p] = u & 3;
        int o = SWZ(bun[p], buk[p]); bw0[p] = Bs0 + o; bw1[p] = Bs1 + o;
    }
    int aoff[MP], boff[NP];
#pragma unroll
    for (int i = 0; i < MP; ++i) { int m = wrow*(MP*16) + i*16 + lr; aoff[i] = SWZ(m, kq); }
#pragma unroll
    for (int j = 0; j < NP; ++j) { int n = wcol*(NP*16) + j*16 + lr; boff[j] = SWZ(n, kq); }

    f32x4 acc0[MP][NP] = {}; f32x4 acc1[MP][NP] = {};

    const int R = (K1 + K2) / 32;

    auto issue = [&](int rd, U8* aR, U8* bR) {
        const bool ph1 = (rd * 32) < K1;
        const int  kl  = ph1 ? rd * 32 : rd * 32 - K1;
        const int  Ka  = ph1 ? K1 : K2;
        const uint* Ap = ph1 ? (const uint*)A1 : A2;
        const uint* Bp = (const uint*)(ph1 ? B1 : B2);
#pragma unroll
        for (int p = 0; p < AUP; ++p)
            aR[p] = ld8(Ap + (size_t)(m0 + aum[p]) * Ka + kl + auk[p] * 8);
#pragma unroll
        for (int p = 0; p < BUP; ++p)
            bR[p] = ld8(Bp + (size_t)(n0 + bun[p]) * Ka + kl + buk[p] * 8);
    };

    auto stage = [&](U8* aR, U8* bR, bool aF32) {
#pragma unroll
        for (int p = 0; p < AUP; ++p) {
            half8 lo, hi;
            if (aF32) split8(aR[p], lo, hi); else unpack8(aR[p], lo, hi);
            *(half8*)aw0[p] = lo; *(half8*)aw1[p] = hi;
        }
#pragma unroll
        for (int p = 0; p < BUP; ++p) {
            half8 lo, hi;
            if (b_f32) split8(bR[p], lo, hi); else unpack8(bR[p], lo, hi);
            *(half8*)bw0[p] = lo; *(half8*)bw1[p] = hi;
        }
    };

    auto compute = [&]() {
        half8 a0[MP], a1[MP], b0[NP], b1[NP];
#pragma unroll
        for (int i = 0; i < MP; ++i) {
            a0[i] = *(const half8*)(As0 + aoff[i]);
            a1[i] = *(const half8*)(As1 + aoff[i]);
        }
#pragma unroll
        for (int j = 0; j < NP; ++j) {
            b0[j] = *(const half8*)(Bs0 + boff[j]);
            b1[j] = *(const half8*)(Bs1 + boff[j]);
        }
#pragma unroll
        for (int i = 0; i < MP; ++i)
#pragma unroll
            for (int j = 0; j < NP; ++j) {
                acc0[i][j] = __builtin_amdgcn_mfma_f32_16x16x32_f16(a0[i], b0[j], acc0[i][j], 0, 0, 0);
                acc1[i][j] = __builtin_amdgcn_mfma_f32_16x16x32_f16(a1[i], b0[j], acc1[i][j], 0, 0, 0);
                acc1[i][j] = __builtin_amdgcn_mfma_f32_16x16x32_f16(a0[i], b1[j], acc1[i][j], 0, 0, 0);
            }
    };

    U8 aA[AUP], bA[BUP], aB[AUP], bB[BUP];
    issue(0, aA, bA);
    for (int rd = 0; rd < R; rd += 2) {
        if (rd + 1 < R) issue(rd + 1, aB, bB);
        stage(aA, bA, (rd * 32) < K1);
        __syncthreads();
        compute();
        __syncthreads();
        if (rd + 1 < R) {
            if (rd + 2 < R) issue(rd + 2, aA, bA);
            stage(aB, bB, ((rd + 1) * 32) < K1);
            __syncthreads();
            compute();
            __syncthreads();
        }
    }

#pragma unroll
    for (int j = 0; j < NP; ++j) {
        const int n = n0 + wcol*(NP*16) + j*16 + lr;
        float bb = bias1 ? bias1[n] : 0.f;
        if (bias2) bb += bias2[n];
#pragma unroll
        for (int i = 0; i < MP; ++i) {
            const int mb = m0 + wrow*(MP*16) + i*16 + kq*4;
#pragma unroll
            for (int r = 0; r < 4; ++r) {
                float val = acc0[i][j][r] + 0x1p-12f * acc1[i][j][r] + bb;
                if (TANH) val = tanhf(val);
                if (PACKOUT)
                    ((uint*)C)[(size_t)(mb + r) * N + n] = pack_split(val);
                else
                    ((float*)C)[(size_t)(mb + r) * N + n] = val;
            }
        }
    }
}

// ---------------------------------------------------------------------------
__global__ __launch_bounds__(256) void split_pack_k(
    const float* __restrict__ s, uint* __restrict__ d, int n)
{
    for (int i = blockIdx.x * 256 + threadIdx.x; i < n; i += gridDim.x * 256)
        d[i] = pack_split(s[i]);
}

// ---------------------------------------------------------------------------
// log_softmax over Isz=512 + argmax==2 flag; logits = sum of NP partials + rob
// ---------------------------------------------------------------------------
template<int NPART>
__global__ __launch_bounds__(256) void logsoftmax_p(
    const float* __restrict__ parts, const float* __restrict__ rob,
    float* __restrict__ out, float* __restrict__ z)
{
    const int b   = blockIdx.x;
    const int tid = threadIdx.x;
    const size_t S = (size_t)Bsz * Isz;
    const float* row = parts + (size_t)b * Isz;

    float v0, v1;
    if (NPART == 1) { v0 = row[tid]; v1 = row[tid + 256]; }
    else {
        v0 = rob[tid]; v1 = rob[tid + 256];
#pragma unroll
        for (int p = 0; p < NPART; ++p) { v0 += row[p*S + tid]; v1 += row[p*S + tid + 256]; }
    }

    float mv; int mi;
    if (v0 >= v1) { mv = v0; mi = tid; } else { mv = v1; mi = tid + 256; }
#pragma unroll
    for (int off = 32; off; off >>= 1) {
        float ov = __shfl_xor(mv, off);
        int   oi = __shfl_xor(mi, off);
        if (ov > mv || (ov == mv && oi < mi)) { mv = ov; mi = oi; }
    }
    __shared__ float smv[4];
    __shared__ int   smi[4];
    const int wid = tid >> 6, lane = tid & 63;
    if (lane == 0) { smv[wid] = mv; smi[wid] = mi; }
    __syncthreads();
    if (tid == 0) {
        for (int w = 1; w < 4; ++w)
            if (smv[w] > smv[0] || (smv[w] == smv[0] && smi[w] < smi[0])) {
                smv[0] = smv[w]; smi[0] = smi[w];
            }
    }
    __syncthreads();
    mv = smv[0]; mi = smi[0];

    float s = expf(v0 - mv) + expf(v1 - mv);
#pragma unroll
    for (int off = 32; off; off >>= 1) s += __shfl_xor(s, off);
    __shared__ float ssum[4];
    if (lane == 0) ssum[wid] = s;
    __syncthreads();
    if (tid == 0) ssum[0] = ssum[0] + ssum[1] + ssum[2] + ssum[3];
    __syncthreads();
    const float ls = logf(ssum[0]);

    float* orow = out + (size_t)b * Isz;
    orow[tid]       = v0 - mv - ls;
    orow[tid + 256] = v1 - mv - ls;
    if (tid == 0) z[b] = (mi == 2) ? 1.f : 0.f;
}

// ---------------------------------------------------------------------------
__global__ __launch_bounds__(64) void blend_done(
    const float* __restrict__ z, float* __restrict__ out)
{
    const int b   = blockIdx.x;
    const int tid = threadIdx.x;
    float done = 0.f;
    for (int t = 0; t < Tdec; ++t) {
        done = fmaxf(done, z[(size_t)t * Bsz + b]);
        if (done > 0.5f) {
            float* row = out + ((size_t)t * Bsz + b) * Isz;
            for (int j = tid; j < Isz; j += 64) row[j] = (j == 0) ? 1.f : 0.f;
        }
    }
}

// ---------------------------------------------------------------------------
extern "C" void kernel_launch(void* const* d_in, const int* in_sizes, int n_in,
                              void* d_out, int out_size, void* d_ws, size_t ws_size,
                              hipStream_t stream)
{
    const float* x    = (const float*)d_in[0];
    const float* eWih = (const float*)d_in[1];
    const float* eWhh = (const float*)d_in[2];
    const float* ebih = (const float*)d_in[3];
    const float* ebhh = (const float*)d_in[4];
    const float* dWhh = (const float*)d_in[6];
    const float* dbih = (const float*)d_in[7];
    const float* dbhh = (const float*)d_in[8];
    const float* roW  = (const float*)d_in[9];
    const float* rob  = (const float*)d_in[10];
    float* out = (float*)d_out;

    const size_t sz_eWih = (size_t)Hsz * Isz * 4;            //  4 MB
    const size_t sz_eWhh = (size_t)Hsz * Hsz * 4;            // 16 MB
    const size_t sz_roW  = (size_t)Isz * Hsz * 4;            //  4 MB
    const size_t sz_h    = (size_t)Bsz * Hsz * 4;            //  8 MB packed
    const size_t sz_part = (size_t)4 * Bsz * Isz * 4;        //  8 MB
    const size_t sz_z    = (size_t)Tdec * Bsz * 4;
    const size_t sz_px   = (size_t)Tenc * Bsz * Isz * 4;     // 136 MB
    const size_t sz_slot = (size_t)Bsz * Isz * 4;            //  2 MB

    const size_t base_need = sz_eWih + 2*sz_eWhh + sz_roW + 2*sz_h + sz_part + sz_z;
    const int mode = (ws_size >= base_need + sz_px) ? 2
                   : (ws_size >= base_need + sz_slot) ? 1 : 0;

    char* ws = (char*)d_ws;

    if (mode >= 1) {
        size_t off = 0;
        uint* pWih  = (uint*)(ws + off); off += sz_eWih;
        uint* pWhh  = (uint*)(ws + off); off += sz_eWhh;
        uint* pdWhh = (uint*)(ws + off); off += sz_eWhh;
        uint* proW  = (uint*)(ws + off); off += sz_roW;
        uint* hA    = (uint*)(ws + off); off += sz_h;
        uint* hB    = (uint*)(ws + off); off += sz_h;
        float* parts= (float*)(ws + off); off += sz_part;
        float* zbuf = (float*)(ws + off); off += sz_z;
        uint* px    = (uint*)(ws + off);   // mode2: 65 steps; mode1: 1-step slot

        split_pack_k<<<dim3(1024), dim3(256), 0, stream>>>(eWih, pWih,  Hsz*Isz);
        split_pack_k<<<dim3(2048), dim3(256), 0, stream>>>(eWhh, pWhh,  Hsz*Hsz);
        split_pack_k<<<dim3(2048), dim3(256), 0, stream>>>(dWhh, pdWhh, Hsz*Hsz);
        split_pack_k<<<dim3(1024), dim3(256), 0, stream>>>(roW,  proW,  Isz*Hsz);
        if (mode == 2)
            split_pack_k<<<dim3(2048), dim3(256), 0, stream>>>(x, px, Tenc*Bsz*Isz);

        hipMemsetAsync(hA, 0, sz_h, stream);

        uint* h[2] = { hA, hB };
        int cur = 0;
        // ---- encoder ----
        for (int t = 0; t < Tenc; ++t) {
            const uint* xs;
            if (mode == 2) xs = px + (size_t)t * Bsz * Isz;
            else {
                split_pack_k<<<dim3(512), dim3(256), 0, stream>>>(
                    x + (size_t)t * Bsz * Isz, px, Bsz*Isz);
                xs = px;
            }
            gemm_pk<true, false><<<dim3(128), dim3(256), 0, stream>>>(
                xs, Isz, pWih, h[cur], Hsz, pWhh,
                ebih, ebhh, h[cur ^ 1], Bsz, Hsz, 8, 16, 1);
            cur ^= 1;
        }
        // ---- decoder ----
        for (int t = 0; t < Tdec; ++t) {
            gemm_pk<true, false><<<dim3(128), dim3(256), 0, stream>>>(
                nullptr, 0, nullptr, h[cur], Hsz, pdWhh,
                dbih, dbhh, h[cur ^ 1], Bsz, Hsz, 8, 16, 1);
            cur ^= 1;
            gemm_pk<false, true><<<dim3(128), dim3(256), 0, stream>>>(
                nullptr, 0, nullptr, h[cur], Hsz, proW,
                nullptr, nullptr, parts, Bsz, Isz, 8, 4, 4);
            logsoftmax_p<4><<<dim3(Bsz), dim3(256), 0, stream>>>(
                parts, rob, out + (size_t)t * Bsz * Isz, zbuf + (size_t)t * Bsz);
        }
        blend_done<<<dim3(Bsz), dim3(64), 0, stream>>>(zbuf, out);
        return;
    }

    // ================= fallback: round-2 path =================
    {
        const size_t sz_lg = (size_t)Bsz * Isz * 4;
        size_t off = 0;
        uint*  hA     = (uint*)(ws + off); off += sz_h;
        uint*  hB     = (uint*)(ws + off); off += sz_h;
        float* logits = (float*)(ws + off); off += sz_lg;
        float* zbuf   = (float*)(ws + off);

        hipMemsetAsync(hA, 0, sz_h, stream);

        uint* h[2] = { hA, hB };
        const dim3 blk(256);
        const dim3 grid_h(Hsz / 128, Bsz / 64);
        const dim3 grid_ro(Isz / 64, Bsz / 64);

        int cur = 0;
        for (int t = 0; t < Tenc; ++t) {
            gemm_sp<64, 128, 2, 2, 2, 4, true, true><<<grid_h, blk, 0, stream>>>(
                x + (size_t)t * Bsz * Isz, Isz, eWih,
                h[cur], Hsz, eWhh, 1,
                ebih, ebhh, h[cur ^ 1], Bsz, Hsz);
            cur ^= 1;
        }
        for (int t = 0; t < Tdec; ++t) {
            gemm_sp<64, 128, 2, 2, 2, 4, true, true><<<grid_h, blk, 0, stream>>>(
                nullptr, 0, nullptr, h[cur], Hsz, dWhh, 1,
                dbih, dbhh, h[cur ^ 1], Bsz, Hsz);
            cur ^= 1;
            gemm_sp<64, 64, 2, 2, 2, 2, false, false><<<grid_ro, blk, 0, stream>>>(
                nullptr, 0, nullptr, h[cur], Hsz, roW, 1,
                rob, nullptr, logits, Bsz, Isz);
            logsoftmax_p<1><<<dim3(Bsz), dim3(256), 0, stream>>>(
                logits, rob, out + (size_t)t * Bsz * Isz, zbuf + (size_t)t * Bsz);
        }
        blend_done<<<dim3(Bsz), dim3(64), 0, stream>>>(zbuf, out);
    }
}

// Round 4
// 8723.076 us; speedup vs baseline: 2.8170x; 1.4152x over previous
//
#include <hip/hip_runtime.h>
#include <math.h>

// Problem constants (VanillaRNN: T=129, B=1024, I=512, H=2048, k=63)
constexpr int Bsz  = 1024;
constexpr int Isz  = 512;
constexpr int Hsz  = 2048;
constexpr int Tenc = 65;   // k+2 encoder steps
constexpr int Tdec = 64;   // k+1 decoder steps

typedef _Float16 half8 __attribute__((ext_vector_type(8)));
typedef float    f32x4 __attribute__((ext_vector_type(4)));
typedef unsigned int uint;
typedef unsigned short ushort;

// ---- packed split-fp16 pair: lo = f16(v), hi = f16((v - lo) * 4096) ----
__device__ inline uint pack_split(float v) {
    _Float16 a0 = (_Float16)v;
    float r = (v - (float)a0) * 4096.f;
    _Float16 a1 = (_Float16)r;
    return ((uint)__builtin_bit_cast(ushort, a1) << 16) | __builtin_bit_cast(ushort, a0);
}

struct U8 { uint4 a, b; };
__device__ inline U8 ld8(const uint* __restrict__ p) {
    U8 r; r.a = *(const uint4*)p; r.b = *(const uint4*)(p + 4); return r;
}

// 8 fp32 -> (lo8, hi8) split halves (fallback path)
__device__ inline void split8(const U8& v, half8& lo, half8& hi) {
    union { uint4 u; float f[4]; } A, B;
    A.u = v.a; B.u = v.b;
    float x[8] = {A.f[0], A.f[1], A.f[2], A.f[3], B.f[0], B.f[1], B.f[2], B.f[3]};
#pragma unroll
    for (int e = 0; e < 8; ++e) {
        _Float16 a0 = (_Float16)x[e];
        float r = (x[e] - (float)a0) * 4096.f;
        lo[e] = a0; hi[e] = (_Float16)r;
    }
}

// 8 packed uint32 -> (lo8, hi8) via byte-perm
__device__ inline void unpack8(const U8& v, half8& lo, half8& hi) {
    union { uint u[4]; half8 h; } L, H;
    uint w[8] = {v.a.x, v.a.y, v.a.z, v.a.w, v.b.x, v.b.y, v.b.z, v.b.w};
#pragma unroll
    for (int q = 0; q < 4; ++q) {
        L.u[q] = __builtin_amdgcn_perm(w[2*q+1], w[2*q], 0x05040100u);
        H.u[q] = __builtin_amdgcn_perm(w[2*q+1], w[2*q], 0x07060302u);
    }
    lo = L.h; hi = H.h;
}

// async global(16B) -> LDS, per-lane global src, wave-uniform LDS base
__device__ __forceinline__ void gll16(const uint* g, uint* l) {
    __builtin_amdgcn_global_load_lds(
        (const __attribute__((address_space(1))) void*)(uintptr_t)g,
        (__attribute__((address_space(3))) void*)(unsigned int)(uintptr_t)l,
        16, 0, 0);
}

// ===========================================================================
// FAST PATH: all-packed split-f16 GEMM, global_load_lds staging, depth-2
// pipeline, counted vmcnt. Tile BM=MP*32 x BN=NP*32, 4 waves (2x2),
// wave-tile (MP*16) x (NP*16).
// C = act(bias1+bias2 + A1*B1^T (K1) + A2*B2^T (K2)); all matrices packed
// uint32 (lo f16 | hi f16<<16), row-major [rows][K].
// LDS: row = 32 packed uints (128B = 8x16B units); unit u stored at
// (u ^ (row&7)) -> bank-conflict-free ds_read_b128; inverse swizzle applied
// to the GLOBAL source address (global_load_lds dest must stay linear).
// ===========================================================================
template<int MP, int NP, bool TANH, bool PARTIAL>
__global__ __launch_bounds__(256, 1) void gemm_pk(
    const uint* __restrict__ A1, int K1, const uint* __restrict__ B1,
    const uint* __restrict__ A2, int K2, const uint* __restrict__ B2,
    const float* __restrict__ bias1, const float* __restrict__ bias2,
    void* __restrict__ C, int M, int N, int GM, int GN, int KS)
{
    constexpr int BM = MP * 32, BN = NP * 32;
    constexpr int NV = MP + NP;          // global_load_lds per STAGE per thread

    __shared__ uint ldsA[3 * BM * 32];
    __shared__ uint ldsB[3 * BN * 32];

    const int tid  = threadIdx.x;
    const int wid  = tid >> 6, lane = tid & 63;
    const int wr   = wid >> 1, wc = wid & 1;
    const int kq   = lane >> 4, lr = lane & 15;

    // ---- XCD-stable block decode: n-strip pinned to an XCD ----
    const int L = blockIdx.x, xcd = L & 7, g = L >> 3;
    int n_b, m_b, ks;
    const int spx = GN >> 3;
    if (spx > 0) {
        n_b = xcd * spx + (g % spx);
        int r = g / spx; m_b = r % GM; ks = r / GM;
    } else {
        const int xpn = 8 / GN;
        n_b = xcd / xpn;
        int r = g * xpn + (xcd % xpn); m_b = r % GM; ks = r / GM;
    }
    const int m0 = m_b * BM, n0 = n_b * BN;

    // ---- staging source offsets (uint elements), per issue q ----
    int offA1[MP], offA2[MP], offB1[NP], offB2[NP];
#pragma unroll
    for (int q = 0; q < MP; ++q) {
        int U = q * 256 + tid, row = U >> 3, us = U & 7;
        int u = us ^ (row & 7);                   // inverse read-swizzle on SOURCE
        offA1[q] = (m0 + row) * K1 + u * 4;
        offA2[q] = (m0 + row) * K2 + u * 4;
    }
#pragma unroll
    for (int q = 0; q < NP; ++q) {
        int U = q * 256 + tid, row = U >> 3, us = U & 7;
        int u = us ^ (row & 7);
        offB1[q] = (n0 + row) * K1 + u * 4;
        offB2[q] = (n0 + row) * K2 + u * 4;
    }
    const int ldsbase = (tid & ~63) * 4;          // wave-uniform, uints

    const int R1 = K1 / 32;
    const int R  = (K1 + K2) / 32;
    const int nr = R / KS;
    const int r0 = ks * nr;

    auto STAGE = [&](int r, int bi) {
        uint* Ab = ldsA + bi * (BM * 32);
        uint* Bb = ldsB + bi * (BN * 32);
        const bool ph1 = r < R1;
        const int kl = (ph1 ? r : r - R1) * 32;
        const uint* As = ph1 ? A1 : A2;
        const uint* Bs = ph1 ? B1 : B2;
#pragma unroll
        for (int q = 0; q < MP; ++q)
            gll16(As + (ph1 ? offA1[q] : offA2[q]) + kl, Ab + q * 1024 + ldsbase);
#pragma unroll
        for (int q = 0; q < NP; ++q)
            gll16(Bs + (ph1 ? offB1[q] : offB2[q]) + kl, Bb + q * 1024 + ldsbase);
    };

    f32x4 acc0[MP][NP] = {}; f32x4 acc1[MP][NP] = {};

    auto FRAG = [&](const uint* buf, int row, half8& lo, half8& hi) {
        const int b = row * 8, s = row & 7;
        U8 v;
        v.a = *(const uint4*)(buf + (b + ((2 * kq)     ^ s)) * 4);
        v.b = *(const uint4*)(buf + (b + ((2 * kq + 1) ^ s)) * 4);
        unpack8(v, lo, hi);
    };

    auto COMPUTE = [&](int bi) {
        const uint* Ab = ldsA + bi * (BM * 32);
        const uint* Bb = ldsB + bi * (BN * 32);
        half8 a0[MP], a1[MP];
#pragma unroll
        for (int i = 0; i < MP; ++i) FRAG(Ab, wr * (MP*16) + i * 16 + lr, a0[i], a1[i]);
#pragma unroll
        for (int j = 0; j < NP; ++j) {
            half8 b0, b1;
            FRAG(Bb, wc * (NP*16) + j * 16 + lr, b0, b1);
#pragma unroll
            for (int i = 0; i < MP; ++i) {
                acc0[i][j] = __builtin_amdgcn_mfma_f32_16x16x32_f16(a0[i], b0, acc0[i][j], 0, 0, 0);
                acc1[i][j] = __builtin_amdgcn_mfma_f32_16x16x32_f16(a1[i], b0, acc1[i][j], 0, 0, 0);
                acc1[i][j] = __builtin_amdgcn_mfma_f32_16x16x32_f16(a0[i], b1, acc1[i][j], 0, 0, 0);
            }
        }
    };

    // ---- prologue: stage rounds r0, r0+1 ----
    STAGE(r0, 0);
    STAGE(r0 + 1, 1);
    __builtin_amdgcn_sched_barrier(0);
    asm volatile("s_waitcnt vmcnt(%0)" :: "i"(NV) : "memory");
    __builtin_amdgcn_s_barrier();
    __builtin_amdgcn_sched_barrier(0);

    // ---- main loop ----
    int bi = 0;
    for (int t = 0; t < nr; ++t) {
        const bool more = (t + 2 < nr);
        if (more) {
            int b2 = bi + 2; if (b2 >= 3) b2 -= 3;
            STAGE(r0 + t + 2, b2);
        }
        COMPUTE(bi);
        __builtin_amdgcn_sched_barrier(0);
        if (more) asm volatile("s_waitcnt vmcnt(%0)" :: "i"(NV) : "memory");
        else      asm volatile("s_waitcnt vmcnt(0)" ::: "memory");
        __builtin_amdgcn_s_barrier();
        __builtin_amdgcn_sched_barrier(0);
        if (++bi == 3) bi = 0;
    }

    // ---- epilogue ----
#pragma unroll
    for (int j = 0; j < NP; ++j) {
        const int n = n0 + wc * (NP*16) + j * 16 + lr;
        float bb = 0.f;
        if (!PARTIAL) {
            bb = bias1 ? bias1[n] : 0.f;
            if (bias2) bb += bias2[n];
        }
#pragma unroll
        for (int i = 0; i < MP; ++i) {
            const int mb = m0 + wr * (MP*16) + i * 16 + kq * 4;
#pragma unroll
            for (int r = 0; r < 4; ++r) {
                float val = acc0[i][j][r] + 0x1p-12f * acc1[i][j][r] + bb;
                if (PARTIAL) {
                    ((float*)C)[(size_t)ks * M * N + (size_t)(mb + r) * N + n] = val;
                } else {
                    if (TANH) val = tanhf(val);
                    ((uint*)C)[(size_t)(mb + r) * N + n] = pack_split(val);
                }
            }
        }
    }
}

// ===========================================================================
// FALLBACK PATH (reg-staged; handles fp32 B when ws tiny)
// ===========================================================================
#define SWZ(row, kk) (((row) * 4 + ((kk) ^ (((row) >> 1) & 3))) * 8)

template<int BM, int BN, int WR, int WC, int MP, int NP, bool TANH, bool PACKOUT>
__global__ __launch_bounds__(WR*WC*64) void gemm_sp(
    const float* __restrict__ A1, int K1, const void* __restrict__ B1,
    const uint*  __restrict__ A2, int K2, const void* __restrict__ B2,
    int b_f32,
    const float* __restrict__ bias1, const float* __restrict__ bias2,
    void* __restrict__ C, int M, int N)
{
    constexpr int NT  = WR * WC * 64;
    constexpr int AUP = BM * 4 / NT;
    constexpr int BUP = BN * 4 / NT;

    __shared__ __align__(16) _Float16 As0[BM*32], As1[BM*32];
    __shared__ __align__(16) _Float16 Bs0[BN*32], Bs1[BN*32];

    const int tid  = threadIdx.x;
    const int wid  = tid >> 6, lane = tid & 63;
    const int wrow = wid / WC, wcol = wid % WC;
    const int kq   = lane >> 4, lr = lane & 15;
    const int m0   = blockIdx.y * BM;
    const int n0   = blockIdx.x * BN;

    int aum[AUP], auk[AUP]; _Float16 *aw0[AUP], *aw1[AUP];
#pragma unroll
    for (int p = 0; p < AUP; ++p) {
        int u = tid + p * NT; aum[p] = u >> 2; auk[p] = u & 3;
        int o = SWZ(aum[p], auk[p]); aw0[p] = As0 + o; aw1[p] = As1 + o;
    }
    int bun[BUP], buk[BUP]; _Float16 *bw0[BUP], *bw1[BUP];
#pragma unroll
    for (int p = 0; p < BUP; ++p) {
        int u = tid + p * NT; bun[p] = u >> 2; buk[p] = u & 3;
        int o = SWZ(bun[p], buk[p]); bw0[p] = Bs0 + o; bw1[p] = Bs1 + o;
    }
    int aoff[MP], boff[NP];
#pragma unroll
    for (int i = 0; i < MP; ++i) { int m = wrow*(MP*16) + i*16 + lr; aoff[i] = SWZ(m, kq); }
#pragma unroll
    for (int j = 0; j < NP; ++j) { int n = wcol*(NP*16) + j*16 + lr; boff[j] = SWZ(n, kq); }

    f32x4 acc0[MP][NP] = {}; f32x4 acc1[MP][NP] = {};

    const int R = (K1 + K2) / 32;

    auto issue = [&](int rd, U8* aR, U8* bR) {
        const bool ph1 = (rd * 32) < K1;
        const int  kl  = ph1 ? rd * 32 : rd * 32 - K1;
        const int  Ka  = ph1 ? K1 : K2;
        const uint* Ap = ph1 ? (const uint*)A1 : A2;
        const uint* Bp = (const uint*)(ph1 ? B1 : B2);
#pragma unroll
        for (int p = 0; p < AUP; ++p)
            aR[p] = ld8(Ap + (size_t)(m0 + aum[p]) * Ka + kl + auk[p] * 8);
#pragma unroll
        for (int p = 0; p < BUP; ++p)
            bR[p] = ld8(Bp + (size_t)(n0 + bun[p]) * Ka + kl + buk[p] * 8);
    };

    auto stage = [&](U8* aR, U8* bR, bool aF32) {
#pragma unroll
        for (int p = 0; p < AUP; ++p) {
            half8 lo, hi;
            if (aF32) split8(aR[p], lo, hi); else unpack8(aR[p], lo, hi);
            *(half8*)aw0[p] = lo; *(half8*)aw1[p] = hi;
        }
#pragma unroll
        for (int p = 0; p < BUP; ++p) {
            half8 lo, hi;
            if (b_f32) split8(bR[p], lo, hi); else unpack8(bR[p], lo, hi);
            *(half8*)bw0[p] = lo; *(half8*)bw1[p] = hi;
        }
    };

    auto compute = [&]() {
        half8 a0[MP], a1[MP], b0[NP], b1[NP];
#pragma unroll
        for (int i = 0; i < MP; ++i) {
            a0[i] = *(const half8*)(As0 + aoff[i]);
            a1[i] = *(const half8*)(As1 + aoff[i]);
        }
#pragma unroll
        for (int j = 0; j < NP; ++j) {
            b0[j] = *(const half8*)(Bs0 + boff[j]);
            b1[j] = *(const half8*)(Bs1 + boff[j]);
        }
#pragma unroll
        for (int i = 0; i < MP; ++i)
#pragma unroll
            for (int j = 0; j < NP; ++j) {
                acc0[i][j] = __builtin_amdgcn_mfma_f32_16x16x32_f16(a0[i], b0[j], acc0[i][j], 0, 0, 0);
                acc1[i][j] = __builtin_amdgcn_mfma_f32_16x16x32_f16(a1[i], b0[j], acc1[i][j], 0, 0, 0);
                acc1[i][j] = __builtin_amdgcn_mfma_f32_16x16x32_f16(a0[i], b1[j], acc1[i][j], 0, 0, 0);
            }
    };

    U8 aA[AUP], bA[BUP], aB[AUP], bB[BUP];
    issue(0, aA, bA);
    for (int rd = 0; rd < R; rd += 2) {
        if (rd + 1 < R) issue(rd + 1, aB, bB);
        stage(aA, bA, (rd * 32) < K1);
        __syncthreads();
        compute();
        __syncthreads();
        if (rd + 1 < R) {
            if (rd + 2 < R) issue(rd + 2, aA, bA);
            stage(aB, bB, ((rd + 1) * 32) < K1);
            __syncthreads();
            compute();
            __syncthreads();
        }
    }

#pragma unroll
    for (int j = 0; j < NP; ++j) {
        const int n = n0 + wcol*(NP*16) + j*16 + lr;
        float bb = bias1 ? bias1[n] : 0.f;
        if (bias2) bb += bias2[n];
#pragma unroll
        for (int i = 0; i < MP; ++i) {
            const int mb = m0 + wrow*(MP*16) + i*16 + kq*4;
#pragma unroll
            for (int r = 0; r < 4; ++r) {
                float val = acc0[i][j][r] + 0x1p-12f * acc1[i][j][r] + bb;
                if (TANH) val = tanhf(val);
                if (PACKOUT)
                    ((uint*)C)[(size_t)(mb + r) * N + n] = pack_split(val);
                else
                    ((float*)C)[(size_t)(mb + r) * N + n] = val;
            }
        }
    }
}

// ---------------------------------------------------------------------------
__global__ __launch_bounds__(256) void split_pack_k(
    const float* __restrict__ s, uint* __restrict__ d, int n)
{
    for (int i = blockIdx.x * 256 + threadIdx.x; i < n; i += gridDim.x * 256)
        d[i] = pack_split(s[i]);
}

// ---------------------------------------------------------------------------
// log_softmax over Isz=512 + argmax==2 flag; logits = sum of NP partials + rob
// ---------------------------------------------------------------------------
template<int NPART>
__global__ __launch_bounds__(256) void logsoftmax_p(
    const float* __restrict__ parts, const float* __restrict__ rob,
    float* __restrict__ out, float* __restrict__ z)
{
    const int b   = blockIdx.x;
    const int tid = threadIdx.x;
    const size_t S = (size_t)Bsz * Isz;
    const float* row = parts + (size_t)b * Isz;

    float v0, v1;
    if (NPART == 1) { v0 = row[tid]; v1 = row[tid + 256]; }
    else {
        v0 = rob[tid]; v1 = rob[tid + 256];
#pragma unroll
        for (int p = 0; p < NPART; ++p) { v0 += row[p*S + tid]; v1 += row[p*S + tid + 256]; }
    }

    float mv; int mi;
    if (v0 >= v1) { mv = v0; mi = tid; } else { mv = v1; mi = tid + 256; }
#pragma unroll
    for (int off = 32; off; off >>= 1) {
        float ov = __shfl_xor(mv, off);
        int   oi = __shfl_xor(mi, off);
        if (ov > mv || (ov == mv && oi < mi)) { mv = ov; mi = oi; }
    }
    __shared__ float smv[4];
    __shared__ int   smi[4];
    const int wid = tid >> 6, lane = tid & 63;
    if (lane == 0) { smv[wid] = mv; smi[wid] = mi; }
    __syncthreads();
    if (tid == 0) {
        for (int w = 1; w < 4; ++w)
            if (smv[w] > smv[0] || (smv[w] == smv[0] && smi[w] < smi[0])) {
                smv[0] = smv[w]; smi[0] = smi[w];
            }
    }
    __syncthreads();
    mv = smv[0]; mi = smi[0];

    float s = expf(v0 - mv) + expf(v1 - mv);
#pragma unroll
    for (int off = 32; off; off >>= 1) s += __shfl_xor(s, off);
    __shared__ float ssum[4];
    if (lane == 0) ssum[wid] = s;
    __syncthreads();
    if (tid == 0) ssum[0] = ssum[0] + ssum[1] + ssum[2] + ssum[3];
    __syncthreads();
    const float ls = logf(ssum[0]);

    float* orow = out + (size_t)b * Isz;
    orow[tid]       = v0 - mv - ls;
    orow[tid + 256] = v1 - mv - ls;
    if (tid == 0) z[b] = (mi == 2) ? 1.f : 0.f;
}

// ---------------------------------------------------------------------------
__global__ __launch_bounds__(64) void blend_done(
    const float* __restrict__ z, float* __restrict__ out)
{
    const int b   = blockIdx.x;
    const int tid = threadIdx.x;
    float done = 0.f;
    for (int t = 0; t < Tdec; ++t) {
        done = fmaxf(done, z[(size_t)t * Bsz + b]);
        if (done > 0.5f) {
            float* row = out + ((size_t)t * Bsz + b) * Isz;
            for (int j = tid; j < Isz; j += 64) row[j] = (j == 0) ? 1.f : 0.f;
        }
    }
}

// ---------------------------------------------------------------------------
extern "C" void kernel_launch(void* const* d_in, const int* in_sizes, int n_in,
                              void* d_out, int out_size, void* d_ws, size_t ws_size,
                              hipStream_t stream)
{
    const float* x    = (const float*)d_in[0];
    const float* eWih = (const float*)d_in[1];
    const float* eWhh = (const float*)d_in[2];
    const float* ebih = (const float*)d_in[3];
    const float* ebhh = (const float*)d_in[4];
    const float* dWhh = (const float*)d_in[6];
    const float* dbih = (const float*)d_in[7];
    const float* dbhh = (const float*)d_in[8];
    const float* roW  = (const float*)d_in[9];
    const float* rob  = (const float*)d_in[10];
    float* out = (float*)d_out;

    const size_t sz_eWih = (size_t)Hsz * Isz * 4;            //  4 MB
    const size_t sz_eWhh = (size_t)Hsz * Hsz * 4;            // 16 MB
    const size_t sz_roW  = (size_t)Isz * Hsz * 4;            //  4 MB
    const size_t sz_h    = (size_t)Bsz * Hsz * 4;            //  8 MB packed
    const size_t sz_part = (size_t)4 * Bsz * Isz * 4;        //  8 MB
    const size_t sz_z    = (size_t)Tdec * Bsz * 4;
    const size_t sz_px   = (size_t)Tenc * Bsz * Isz * 4;     // 136 MB
    const size_t sz_slot = (size_t)Bsz * Isz * 4;            //  2 MB

    const size_t base_need = sz_eWih + 2*sz_eWhh + sz_roW + 2*sz_h + sz_part + sz_z;
    const int mode = (ws_size >= base_need + sz_px) ? 2
                   : (ws_size >= base_need + sz_slot) ? 1 : 0;

    char* ws = (char*)d_ws;

    if (mode >= 1) {
        size_t off = 0;
        uint* pWih  = (uint*)(ws + off); off += sz_eWih;
        uint* pWhh  = (uint*)(ws + off); off += sz_eWhh;
        uint* pdWhh = (uint*)(ws + off); off += sz_eWhh;
        uint* proW  = (uint*)(ws + off); off += sz_roW;
        uint* hA    = (uint*)(ws + off); off += sz_h;
        uint* hB    = (uint*)(ws + off); off += sz_h;
        float* parts= (float*)(ws + off); off += sz_part;
        float* zbuf = (float*)(ws + off); off += sz_z;
        uint* px    = (uint*)(ws + off);   // mode2: 65 steps; mode1: 1-step slot

        split_pack_k<<<dim3(1024), dim3(256), 0, stream>>>(eWih, pWih,  Hsz*Isz);
        split_pack_k<<<dim3(2048), dim3(256), 0, stream>>>(eWhh, pWhh,  Hsz*Hsz);
        split_pack_k<<<dim3(2048), dim3(256), 0, stream>>>(dWhh, pdWhh, Hsz*Hsz);
        split_pack_k<<<dim3(1024), dim3(256), 0, stream>>>(roW,  proW,  Isz*Hsz);
        if (mode == 2)
            split_pack_k<<<dim3(2048), dim3(256), 0, stream>>>(x, px, Tenc*Bsz*Isz);

        hipMemsetAsync(hA, 0, sz_h, stream);

        uint* h[2] = { hA, hB };
        int cur = 0;
        // ---- encoder: 256 blocks (16x16), K = 512 + 2048 ----
        for (int t = 0; t < Tenc; ++t) {
            const uint* xs;
            if (mode == 2) xs = px + (size_t)t * Bsz * Isz;
            else {
                split_pack_k<<<dim3(512), dim3(256), 0, stream>>>(
                    x + (size_t)t * Bsz * Isz, px, Bsz*Isz);
                xs = px;
            }
            gemm_pk<2, 4, true, false><<<dim3(256), dim3(256), 0, stream>>>(
                xs, Isz, pWih, h[cur], Hsz, pWhh,
                ebih, ebhh, h[cur ^ 1], Bsz, Hsz, 16, 16, 1);
            cur ^= 1;
        }
        // ---- decoder ----
        for (int t = 0; t < Tdec; ++t) {
            gemm_pk<2, 4, true, false><<<dim3(256), dim3(256), 0, stream>>>(
                nullptr, 0, nullptr, h[cur], Hsz, pdWhh,
                dbih, dbhh, h[cur ^ 1], Bsz, Hsz, 16, 16, 1);
            cur ^= 1;
            gemm_pk<2, 4, false, true><<<dim3(256), dim3(256), 0, stream>>>(
                nullptr, 0, nullptr, h[cur], Hsz, proW,
                nullptr, nullptr, parts, Bsz, Isz, 16, 4, 4);
            logsoftmax_p<4><<<dim3(Bsz), dim3(256), 0, stream>>>(
                parts, rob, out + (size_t)t * Bsz * Isz, zbuf + (size_t)t * Bsz);
        }
        blend_done<<<dim3(Bsz), dim3(64), 0, stream>>>(zbuf, out);
        return;
    }

    // ================= fallback path =================
    {
        const size_t sz_lg = (size_t)Bsz * Isz * 4;
        size_t off = 0;
        uint*  hA     = (uint*)(ws + off); off += sz_h;
        uint*  hB     = (uint*)(ws + off); off += sz_h;
        float* logits = (float*)(ws + off); off += sz_lg;
        float* zbuf   = (float*)(ws + off);

        hipMemsetAsync(hA, 0, sz_h, stream);

        uint* h[2] = { hA, hB };
        const dim3 blk(256);
        const dim3 grid_h(Hsz / 128, Bsz / 64);
        const dim3 grid_ro(Isz / 64, Bsz / 64);

        int cur = 0;
        for (int t = 0; t < Tenc; ++t) {
            gemm_sp<64, 128, 2, 2, 2, 4, true, true><<<grid_h, blk, 0, stream>>>(
                x + (size_t)t * Bsz * Isz, Isz, eWih,
                h[cur], Hsz, eWhh, 1,
                ebih, ebhh, h[cur ^ 1], Bsz, Hsz);
            cur ^= 1;
        }
        for (int t = 0; t < Tdec; ++t) {
            gemm_sp<64, 128, 2, 2, 2, 4, true, true><<<grid_h, blk, 0, stream>>>(
                nullptr, 0, nullptr, h[cur], Hsz, dWhh, 1,
                dbih, dbhh, h[cur ^ 1], Bsz, Hsz);
            cur ^= 1;
            gemm_sp<64, 64, 2, 2, 2, 2, false, false><<<grid_ro, blk, 0, stream>>>(
                nullptr, 0, nullptr, h[cur], Hsz, roW, 1,
                rob, nullptr, logits, Bsz, Isz);
            logsoftmax_p<1><<<dim3(Bsz), dim3(256), 0, stream>>>(
                logits, rob, out + (size_t)t * Bsz * Isz, zbuf + (size_t)t * Bsz);
        }
        blend_done<<<dim3(Bsz), dim3(64), 0, stream>>>(zbuf, out);
    }
}

// Round 5
// 8355.448 us; speedup vs baseline: 2.9410x; 1.0440x over previous
//
#include <hip/hip_runtime.h>
#include <math.h>

// Problem constants (VanillaRNN: T=129, B=1024, I=512, H=2048, k=63)
constexpr int Bsz  = 1024;
constexpr int Isz  = 512;
constexpr int Hsz  = 2048;
constexpr int Tenc = 65;   // k+2 encoder steps
constexpr int Tdec = 64;   // k+1 decoder steps

typedef _Float16 half8 __attribute__((ext_vector_type(8)));
typedef float    f32x4 __attribute__((ext_vector_type(4)));
typedef unsigned int uint;
typedef unsigned short ushort;

// ---- packed split-fp16 pair: lo = f16(v), hi = f16((v - lo) * 4096) ----
__device__ inline uint pack_split(float v) {
    _Float16 a0 = (_Float16)v;
    float r = (v - (float)a0) * 4096.f;
    _Float16 a1 = (_Float16)r;
    return ((uint)__builtin_bit_cast(ushort, a1) << 16) | __builtin_bit_cast(ushort, a0);
}

struct U8 { uint4 a, b; };
__device__ inline U8 ld8(const uint* __restrict__ p) {
    U8 r; r.a = *(const uint4*)p; r.b = *(const uint4*)(p + 4); return r;
}

// 8 fp32 -> (lo8, hi8) split halves (fallback path)
__device__ inline void split8(const U8& v, half8& lo, half8& hi) {
    union { uint4 u; float f[4]; } A, B;
    A.u = v.a; B.u = v.b;
    float x[8] = {A.f[0], A.f[1], A.f[2], A.f[3], B.f[0], B.f[1], B.f[2], B.f[3]};
#pragma unroll
    for (int e = 0; e < 8; ++e) {
        _Float16 a0 = (_Float16)x[e];
        float r = (x[e] - (float)a0) * 4096.f;
        lo[e] = a0; hi[e] = (_Float16)r;
    }
}

// 8 packed uint32 -> (lo8, hi8) via byte-perm
__device__ inline void unpack8(const U8& v, half8& lo, half8& hi) {
    union { uint u[4]; half8 h; } L, H;
    uint w[8] = {v.a.x, v.a.y, v.a.z, v.a.w, v.b.x, v.b.y, v.b.z, v.b.w};
#pragma unroll
    for (int q = 0; q < 4; ++q) {
        L.u[q] = __builtin_amdgcn_perm(w[2*q+1], w[2*q], 0x05040100u);
        H.u[q] = __builtin_amdgcn_perm(w[2*q+1], w[2*q], 0x07060302u);
    }
    lo = L.h; hi = H.h;
}

// async global(16B) -> LDS, per-lane global src, wave-uniform LDS base
__device__ __forceinline__ void gll16(const uint* g, uint* l) {
    __builtin_amdgcn_global_load_lds(
        (const __attribute__((address_space(1))) void*)(uintptr_t)g,
        (__attribute__((address_space(3))) void*)(unsigned int)(uintptr_t)l,
        16, 0, 0);
}

// ===========================================================================
// FAST PATH: all-packed split-f16 GEMM, global_load_lds staging, DEPTH-4
// pipeline (prefetch distance 3), counted vmcnt. Tile BM=MP*32 x BN=NP*32,
// 4 waves (2x2), wave-tile (MP*16) x (NP*16).
// C = act(bias1+bias2 + A1*B1^T (K1) + A2*B2^T (K2)); all matrices packed
// uint32 (lo f16 | hi f16<<16), row-major [rows][K].
// LDS: row = 32 packed uints (128B = 8x16B units); unit u stored at
// (u ^ (row&7)) -> bank-conflict-free ds_read_b128; inverse swizzle applied
// to the GLOBAL source address (global_load_lds dest must stay linear).
// ===========================================================================
template<int MP, int NP, bool TANH, bool PARTIAL>
__global__ __launch_bounds__(256, 1) void gemm_pk(
    const uint* __restrict__ A1, int K1, const uint* __restrict__ B1,
    const uint* __restrict__ A2, int K2, const uint* __restrict__ B2,
    const float* __restrict__ bias1, const float* __restrict__ bias2,
    void* __restrict__ C, int M, int N, int GM, int GN, int KS)
{
    constexpr int BM = MP * 32, BN = NP * 32;
    constexpr int NV = MP + NP;          // global_load_lds per STAGE per thread

    __shared__ uint ldsA[4 * BM * 32];
    __shared__ uint ldsB[4 * BN * 32];

    const int tid  = threadIdx.x;
    const int wid  = tid >> 6, lane = tid & 63;
    const int wr   = wid >> 1, wc = wid & 1;
    const int kq   = lane >> 4, lr = lane & 15;

    // ---- XCD-stable block decode: n-strip pinned to an XCD ----
    const int L = blockIdx.x, xcd = L & 7, g = L >> 3;
    int n_b, m_b, ks;
    const int spx = GN >> 3;
    if (spx > 0) {
        n_b = xcd * spx + (g % spx);
        int r = g / spx; m_b = r % GM; ks = r / GM;
    } else {
        const int xpn = 8 / GN;
        n_b = xcd / xpn;
        int r = g * xpn + (xcd % xpn); m_b = r % GM; ks = r / GM;
    }
    const int m0 = m_b * BM, n0 = n_b * BN;

    // ---- staging source offsets (uint elements), per issue q ----
    int offA1[MP], offA2[MP], offB1[NP], offB2[NP];
#pragma unroll
    for (int q = 0; q < MP; ++q) {
        int U = q * 256 + tid, row = U >> 3, us = U & 7;
        int u = us ^ (row & 7);                   // inverse read-swizzle on SOURCE
        offA1[q] = (m0 + row) * K1 + u * 4;
        offA2[q] = (m0 + row) * K2 + u * 4;
    }
#pragma unroll
    for (int q = 0; q < NP; ++q) {
        int U = q * 256 + tid, row = U >> 3, us = U & 7;
        int u = us ^ (row & 7);
        offB1[q] = (n0 + row) * K1 + u * 4;
        offB2[q] = (n0 + row) * K2 + u * 4;
    }
    const int ldsbase = (tid & ~63) * 4;          // wave-uniform, uints

    const int R1 = K1 / 32;
    const int R  = (K1 + K2) / 32;
    const int nr = R / KS;
    const int r0 = ks * nr;

    auto STAGE = [&](int r, int bi) {
        uint* Ab = ldsA + bi * (BM * 32);
        uint* Bb = ldsB + bi * (BN * 32);
        const bool ph1 = r < R1;
        const int kl = (ph1 ? r : r - R1) * 32;
        const uint* As = ph1 ? A1 : A2;
        const uint* Bs = ph1 ? B1 : B2;
#pragma unroll
        for (int q = 0; q < MP; ++q)
            gll16(As + (ph1 ? offA1[q] : offA2[q]) + kl, Ab + q * 1024 + ldsbase);
#pragma unroll
        for (int q = 0; q < NP; ++q)
            gll16(Bs + (ph1 ? offB1[q] : offB2[q]) + kl, Bb + q * 1024 + ldsbase);
    };

    f32x4 acc0[MP][NP] = {}; f32x4 acc1[MP][NP] = {};

    auto FRAG = [&](const uint* buf, int row, half8& lo, half8& hi) {
        const int b = row * 8, s = row & 7;
        U8 v;
        v.a = *(const uint4*)(buf + (b + ((2 * kq)     ^ s)) * 4);
        v.b = *(const uint4*)(buf + (b + ((2 * kq + 1) ^ s)) * 4);
        unpack8(v, lo, hi);
    };

    auto COMPUTE = [&](int bi) {
        const uint* Ab = ldsA + bi * (BM * 32);
        const uint* Bb = ldsB + bi * (BN * 32);
        half8 a0[MP], a1[MP];
#pragma unroll
        for (int i = 0; i < MP; ++i) FRAG(Ab, wr * (MP*16) + i * 16 + lr, a0[i], a1[i]);
#pragma unroll
        for (int j = 0; j < NP; ++j) {
            half8 b0, b1;
            FRAG(Bb, wc * (NP*16) + j * 16 + lr, b0, b1);
#pragma unroll
            for (int i = 0; i < MP; ++i) {
                acc0[i][j] = __builtin_amdgcn_mfma_f32_16x16x32_f16(a0[i], b0, acc0[i][j], 0, 0, 0);
                acc1[i][j] = __builtin_amdgcn_mfma_f32_16x16x32_f16(a1[i], b0, acc1[i][j], 0, 0, 0);
                acc1[i][j] = __builtin_amdgcn_mfma_f32_16x16x32_f16(a0[i], b1, acc1[i][j], 0, 0, 0);
            }
        }
    };

    // ---- prologue: stage rounds r0..r0+2 (depth-4, prefetch distance 3) ----
    STAGE(r0,     0);
    STAGE(r0 + 1, 1);
    STAGE(r0 + 2, 2);
    __builtin_amdgcn_sched_barrier(0);
    asm volatile("s_waitcnt vmcnt(%0)" :: "i"(2 * NV) : "memory");
    __builtin_amdgcn_s_barrier();
    __builtin_amdgcn_sched_barrier(0);

    // ---- main loop ----
    int bi = 0;
    for (int t = 0; t < nr; ++t) {
        if (t + 3 < nr) STAGE(r0 + t + 3, (bi + 3) & 3);
        COMPUTE(bi);
        __builtin_amdgcn_sched_barrier(0);
        // rounds still in flight after this wait must exclude round t+1
        const int last = (t + 3 < nr) ? t + 3 : nr - 1;
        const int rem  = last - (t + 1);
        if (rem >= 2)      asm volatile("s_waitcnt vmcnt(%0)" :: "i"(2 * NV) : "memory");
        else if (rem == 1) asm volatile("s_waitcnt vmcnt(%0)" :: "i"(NV) : "memory");
        else               asm volatile("s_waitcnt vmcnt(0)" ::: "memory");
        __builtin_amdgcn_s_barrier();
        __builtin_amdgcn_sched_barrier(0);
        bi = (bi + 1) & 3;
    }

    // ---- epilogue ----
#pragma unroll
    for (int j = 0; j < NP; ++j) {
        const int n = n0 + wc * (NP*16) + j * 16 + lr;
        float bb = 0.f;
        if (!PARTIAL) {
            bb = bias1 ? bias1[n] : 0.f;
            if (bias2) bb += bias2[n];
        }
#pragma unroll
        for (int i = 0; i < MP; ++i) {
            const int mb = m0 + wr * (MP*16) + i * 16 + kq * 4;
#pragma unroll
            for (int r = 0; r < 4; ++r) {
                float val = acc0[i][j][r] + 0x1p-12f * acc1[i][j][r] + bb;
                if (PARTIAL) {
                    ((float*)C)[(size_t)ks * M * N + (size_t)(mb + r) * N + n] = val;
                } else {
                    if (TANH) val = tanhf(val);
                    ((uint*)C)[(size_t)(mb + r) * N + n] = pack_split(val);
                }
            }
        }
    }
}

// ===========================================================================
// FALLBACK PATH (reg-staged; handles fp32 B when ws tiny)
// ===========================================================================
#define SWZ(row, kk) (((row) * 4 + ((kk) ^ (((row) >> 1) & 3))) * 8)

template<int BM, int BN, int WR, int WC, int MP, int NP, bool TANH, bool PACKOUT>
__global__ __launch_bounds__(WR*WC*64) void gemm_sp(
    const float* __restrict__ A1, int K1, const void* __restrict__ B1,
    const uint*  __restrict__ A2, int K2, const void* __restrict__ B2,
    int b_f32,
    const float* __restrict__ bias1, const float* __restrict__ bias2,
    void* __restrict__ C, int M, int N)
{
    constexpr int NT  = WR * WC * 64;
    constexpr int AUP = BM * 4 / NT;
    constexpr int BUP = BN * 4 / NT;

    __shared__ __align__(16) _Float16 As0[BM*32], As1[BM*32];
    __shared__ __align__(16) _Float16 Bs0[BN*32], Bs1[BN*32];

    const int tid  = threadIdx.x;
    const int wid  = tid >> 6, lane = tid & 63;
    const int wrow = wid / WC, wcol = wid % WC;
    const int kq   = lane >> 4, lr = lane & 15;
    const int m0   = blockIdx.y * BM;
    const int n0   = blockIdx.x * BN;

    int aum[AUP], auk[AUP]; _Float16 *aw0[AUP], *aw1[AUP];
#pragma unroll
    for (int p = 0; p < AUP; ++p) {
        int u = tid + p * NT; aum[p] = u >> 2; auk[p] = u & 3;
        int o = SWZ(aum[p], auk[p]); aw0[p] = As0 + o; aw1[p] = As1 + o;
    }
    int bun[BUP], buk[BUP]; _Float16 *bw0[BUP], *bw1[BUP];
#pragma unroll
    for (int p = 0; p < BUP; ++p) {
        int u = tid + p * NT; bun[p] = u >> 2; buk[p] = u & 3;
        int o = SWZ(bun[p], buk[p]); bw0[p] = Bs0 + o; bw1[p] = Bs1 + o;
    }
    int aoff[MP], boff[NP];
#pragma unroll
    for (int i = 0; i < MP; ++i) { int m = wrow*(MP*16) + i*16 + lr; aoff[i] = SWZ(m, kq); }
#pragma unroll
    for (int j = 0; j < NP; ++j) { int n = wcol*(NP*16) + j*16 + lr; boff[j] = SWZ(n, kq); }

    f32x4 acc0[MP][NP] = {}; f32x4 acc1[MP][NP] = {};

    const int R = (K1 + K2) / 32;

    auto issue = [&](int rd, U8* aR, U8* bR) {
        const bool ph1 = (rd * 32) < K1;
        const int  kl  = ph1 ? rd * 32 : rd * 32 - K1;
        const int  Ka  = ph1 ? K1 : K2;
        const uint* Ap = ph1 ? (const uint*)A1 : A2;
        const uint* Bp = (const uint*)(ph1 ? B1 : B2);
#pragma unroll
        for (int p = 0; p < AUP; ++p)
            aR[p] = ld8(Ap + (size_t)(m0 + aum[p]) * Ka + kl + auk[p] * 8);
#pragma unroll
        for (int p = 0; p < BUP; ++p)
            bR[p] = ld8(Bp + (size_t)(n0 + bun[p]) * Ka + kl + buk[p] * 8);
    };

    auto stage = [&](U8* aR, U8* bR, bool aF32) {
#pragma unroll
        for (int p = 0; p < AUP; ++p) {
            half8 lo, hi;
            if (aF32) split8(aR[p], lo, hi); else unpack8(aR[p], lo, hi);
            *(half8*)aw0[p] = lo; *(half8*)aw1[p] = hi;
        }
#pragma unroll
        for (int p = 0; p < BUP; ++p) {
            half8 lo, hi;
            if (b_f32) split8(bR[p], lo, hi); else unpack8(bR[p], lo, hi);
            *(half8*)bw0[p] = lo; *(half8*)bw1[p] = hi;
        }
    };

    auto compute = [&]() {
        half8 a0[MP], a1[MP], b0[NP], b1[NP];
#pragma unroll
        for (int i = 0; i < MP; ++i) {
            a0[i] = *(const half8*)(As0 + aoff[i]);
            a1[i] = *(const half8*)(As1 + aoff[i]);
        }
#pragma unroll
        for (int j = 0; j < NP; ++j) {
            b0[j] = *(const half8*)(Bs0 + boff[j]);
            b1[j] = *(const half8*)(Bs1 + boff[j]);
        }
#pragma unroll
        for (int i = 0; i < MP; ++i)
#pragma unroll
            for (int j = 0; j < NP; ++j) {
                acc0[i][j] = __builtin_amdgcn_mfma_f32_16x16x32_f16(a0[i], b0[j], acc0[i][j], 0, 0, 0);
                acc1[i][j] = __builtin_amdgcn_mfma_f32_16x16x32_f16(a1[i], b0[j], acc1[i][j], 0, 0, 0);
                acc1[i][j] = __builtin_amdgcn_mfma_f32_16x16x32_f16(a0[i], b1[j], acc1[i][j], 0, 0, 0);
            }
    };

    U8 aA[AUP], bA[BUP], aB[AUP], bB[BUP];
    issue(0, aA, bA);
    for (int rd = 0; rd < R; rd += 2) {
        if (rd + 1 < R) issue(rd + 1, aB, bB);
        stage(aA, bA, (rd * 32) < K1);
        __syncthreads();
        compute();
        __syncthreads();
        if (rd + 1 < R) {
            if (rd + 2 < R) issue(rd + 2, aA, bA);
            stage(aB, bB, ((rd + 1) * 32) < K1);
            __syncthreads();
            compute();
            __syncthreads();
        }
    }

#pragma unroll
    for (int j = 0; j < NP; ++j) {
        const int n = n0 + wcol*(NP*16) + j*16 + lr;
        float bb = bias1 ? bias1[n] : 0.f;
        if (bias2) bb += bias2[n];
#pragma unroll
        for (int i = 0; i < MP; ++i) {
            const int mb = m0 + wrow*(MP*16) + i*16 + kq*4;
#pragma unroll
            for (int r = 0; r < 4; ++r) {
                float val = acc0[i][j][r] + 0x1p-12f * acc1[i][j][r] + bb;
                if (TANH) val = tanhf(val);
                if (PACKOUT)
                    ((uint*)C)[(size_t)(mb + r) * N + n] = pack_split(val);
                else
                    ((float*)C)[(size_t)(mb + r) * N + n] = val;
            }
        }
    }
}

// ---------------------------------------------------------------------------
__global__ __launch_bounds__(256) void split_pack_k(
    const float* __restrict__ s, uint* __restrict__ d, int n)
{
    for (int i = blockIdx.x * 256 + threadIdx.x; i < n; i += gridDim.x * 256)
        d[i] = pack_split(s[i]);
}

// ---------------------------------------------------------------------------
// log_softmax over Isz=512 + argmax==2 flag; logits = sum of NP partials + rob
// ---------------------------------------------------------------------------
template<int NPART>
__global__ __launch_bounds__(256) void logsoftmax_p(
    const float* __restrict__ parts, const float* __restrict__ rob,
    float* __restrict__ out, float* __restrict__ z)
{
    const int b   = blockIdx.x;
    const int tid = threadIdx.x;
    const size_t S = (size_t)Bsz * Isz;
    const float* row = parts + (size_t)b * Isz;

    float v0, v1;
    if (NPART == 1) { v0 = row[tid]; v1 = row[tid + 256]; }
    else {
        v0 = rob[tid]; v1 = rob[tid + 256];
#pragma unroll
        for (int p = 0; p < NPART; ++p) { v0 += row[p*S + tid]; v1 += row[p*S + tid + 256]; }
    }

    float mv; int mi;
    if (v0 >= v1) { mv = v0; mi = tid; } else { mv = v1; mi = tid + 256; }
#pragma unroll
    for (int off = 32; off; off >>= 1) {
        float ov = __shfl_xor(mv, off);
        int   oi = __shfl_xor(mi, off);
        if (ov > mv || (ov == mv && oi < mi)) { mv = ov; mi = oi; }
    }
    __shared__ float smv[4];
    __shared__ int   smi[4];
    const int wid = tid >> 6, lane = tid & 63;
    if (lane == 0) { smv[wid] = mv; smi[wid] = mi; }
    __syncthreads();
    if (tid == 0) {
        for (int w = 1; w < 4; ++w)
            if (smv[w] > smv[0] || (smv[w] == smv[0] && smi[w] < smi[0])) {
                smv[0] = smv[w]; smi[0] = smi[w];
            }
    }
    __syncthreads();
    mv = smv[0]; mi = smi[0];

    float s = expf(v0 - mv) + expf(v1 - mv);
#pragma unroll
    for (int off = 32; off; off >>= 1) s += __shfl_xor(s, off);
    __shared__ float ssum[4];
    if (lane == 0) ssum[wid] = s;
    __syncthreads();
    if (tid == 0) ssum[0] = ssum[0] + ssum[1] + ssum[2] + ssum[3];
    __syncthreads();
    const float ls = logf(ssum[0]);

    float* orow = out + (size_t)b * Isz;
    orow[tid]       = v0 - mv - ls;
    orow[tid + 256] = v1 - mv - ls;
    if (tid == 0) z[b] = (mi == 2) ? 1.f : 0.f;
}

// ---------------------------------------------------------------------------
__global__ __launch_bounds__(64) void blend_done(
    const float* __restrict__ z, float* __restrict__ out)
{
    const int b   = blockIdx.x;
    const int tid = threadIdx.x;
    float done = 0.f;
    for (int t = 0; t < Tdec; ++t) {
        done = fmaxf(done, z[(size_t)t * Bsz + b]);
        if (done > 0.5f) {
            float* row = out + ((size_t)t * Bsz + b) * Isz;
            for (int j = tid; j < Isz; j += 64) row[j] = (j == 0) ? 1.f : 0.f;
        }
    }
}

// ---------------------------------------------------------------------------
extern "C" void kernel_launch(void* const* d_in, const int* in_sizes, int n_in,
                              void* d_out, int out_size, void* d_ws, size_t ws_size,
                              hipStream_t stream)
{
    const float* x    = (const float*)d_in[0];
    const float* eWih = (const float*)d_in[1];
    const float* eWhh = (const float*)d_in[2];
    const float* ebih = (const float*)d_in[3];
    const float* ebhh = (const float*)d_in[4];
    const float* dWhh = (const float*)d_in[6];
    const float* dbih = (const float*)d_in[7];
    const float* dbhh = (const float*)d_in[8];
    const float* roW  = (const float*)d_in[9];
    const float* rob  = (const float*)d_in[10];
    float* out = (float*)d_out;

    const size_t sz_eWih = (size_t)Hsz * Isz * 4;            //  4 MB
    const size_t sz_eWhh = (size_t)Hsz * Hsz * 4;            // 16 MB
    const size_t sz_roW  = (size_t)Isz * Hsz * 4;            //  4 MB
    const size_t sz_h    = (size_t)Bsz * Hsz * 4;            //  8 MB packed
    const size_t sz_part = (size_t)4 * Bsz * Isz * 4;        //  8 MB
    const size_t sz_z    = (size_t)Tdec * Bsz * 4;
    const size_t sz_px   = (size_t)Tenc * Bsz * Isz * 4;     // 136 MB
    const size_t sz_slot = (size_t)Bsz * Isz * 4;            //  2 MB

    const size_t base_need = sz_eWih + 2*sz_eWhh + sz_roW + 2*sz_h + sz_part + sz_z;
    const int mode = (ws_size >= base_need + sz_px) ? 2
                   : (ws_size >= base_need + sz_slot) ? 1 : 0;

    char* ws = (char*)d_ws;

    if (mode >= 1) {
        size_t off = 0;
        uint* pWih  = (uint*)(ws + off); off += sz_eWih;
        uint* pWhh  = (uint*)(ws + off); off += sz_eWhh;
        uint* pdWhh = (uint*)(ws + off); off += sz_eWhh;
        uint* proW  = (uint*)(ws + off); off += sz_roW;
        uint* hA    = (uint*)(ws + off); off += sz_h;
        uint* hB    = (uint*)(ws + off); off += sz_h;
        float* parts= (float*)(ws + off); off += sz_part;
        float* zbuf = (float*)(ws + off); off += sz_z;
        uint* px    = (uint*)(ws + off);   // mode2: 65 steps; mode1: 1-step slot

        split_pack_k<<<dim3(1024), dim3(256), 0, stream>>>(eWih, pWih,  Hsz*Isz);
        split_pack_k<<<dim3(2048), dim3(256), 0, stream>>>(eWhh, pWhh,  Hsz*Hsz);
        split_pack_k<<<dim3(2048), dim3(256), 0, stream>>>(dWhh, pdWhh, Hsz*Hsz);
        split_pack_k<<<dim3(1024), dim3(256), 0, stream>>>(roW,  proW,  Isz*Hsz);
        if (mode == 2)
            split_pack_k<<<dim3(2048), dim3(256), 0, stream>>>(x, px, Tenc*Bsz*Isz);

        hipMemsetAsync(hA, 0, sz_h, stream);

        uint* h[2] = { hA, hB };
        int cur = 0;
        // ---- encoder: 256 blocks (16x16), K = 512 + 2048 ----
        for (int t = 0; t < Tenc; ++t) {
            const uint* xs;
            if (mode == 2) xs = px + (size_t)t * Bsz * Isz;
            else {
                split_pack_k<<<dim3(512), dim3(256), 0, stream>>>(
                    x + (size_t)t * Bsz * Isz, px, Bsz*Isz);
                xs = px;
            }
            gemm_pk<2, 4, true, false><<<dim3(256), dim3(256), 0, stream>>>(
                xs, Isz, pWih, h[cur], Hsz, pWhh,
                ebih, ebhh, h[cur ^ 1], Bsz, Hsz, 16, 16, 1);
            cur ^= 1;
        }
        // ---- decoder ----
        for (int t = 0; t < Tdec; ++t) {
            gemm_pk<2, 4, true, false><<<dim3(256), dim3(256), 0, stream>>>(
                nullptr, 0, nullptr, h[cur], Hsz, pdWhh,
                dbih, dbhh, h[cur ^ 1], Bsz, Hsz, 16, 16, 1);
            cur ^= 1;
            gemm_pk<2, 4, false, true><<<dim3(256), dim3(256), 0, stream>>>(
                nullptr, 0, nullptr, h[cur], Hsz, proW,
                nullptr, nullptr, parts, Bsz, Isz, 16, 4, 4);
            logsoftmax_p<4><<<dim3(Bsz), dim3(256), 0, stream>>>(
                parts, rob, out + (size_t)t * Bsz * Isz, zbuf + (size_t)t * Bsz);
        }
        blend_done<<<dim3(Bsz), dim3(64), 0, stream>>>(zbuf, out);
        return;
    }

    // ================= fallback path =================
    {
        const size_t sz_lg = (size_t)Bsz * Isz * 4;
        size_t off = 0;
        uint*  hA     = (uint*)(ws + off); off += sz_h;
        uint*  hB     = (uint*)(ws + off); off += sz_h;
        float* logits = (float*)(ws + off); off += sz_lg;
        float* zbuf   = (float*)(ws + off);

        hipMemsetAsync(hA, 0, sz_h, stream);

        uint* h[2] = { hA, hB };
        const dim3 blk(256);
        const dim3 grid_h(Hsz / 128, Bsz / 64);
        const dim3 grid_ro(Isz / 64, Bsz / 64);

        int cur = 0;
        for (int t = 0; t < Tenc; ++t) {
            gemm_sp<64, 128, 2, 2, 2, 4, true, true><<<grid_h, blk, 0, stream>>>(
                x + (size_t)t * Bsz * Isz, Isz, eWih,
                h[cur], Hsz, eWhh, 1,
                ebih, ebhh, h[cur ^ 1], Bsz, Hsz);
            cur ^= 1;
        }
        for (int t = 0; t < Tdec; ++t) {
            gemm_sp<64, 128, 2, 2, 2, 4, true, true><<<grid_h, blk, 0, stream>>>(
                nullptr, 0, nullptr, h[cur], Hsz, dWhh, 1,
                dbih, dbhh, h[cur ^ 1], Bsz, Hsz);
            cur ^= 1;
            gemm_sp<64, 64, 2, 2, 2, 2, false, false><<<grid_ro, blk, 0, stream>>>(
                nullptr, 0, nullptr, h[cur], Hsz, roW, 1,
                rob, nullptr, logits, Bsz, Isz);
            logsoftmax_p<1><<<dim3(Bsz), dim3(256), 0, stream>>>(
                logits, rob, out + (size_t)t * Bsz * Isz, zbuf + (size_t)t * Bsz);
        }
        blend_done<<<dim3(Bsz), dim3(64), 0, stream>>>(zbuf, out);
    }
}

// Round 6
// 8040.816 us; speedup vs baseline: 3.0561x; 1.0391x over previous
//
#include <hip/hip_runtime.h>
#include <math.h>

// Problem constants (VanillaRNN: T=129, B=1024, I=512, H=2048, k=63)
constexpr int Bsz  = 1024;
constexpr int Isz  = 512;
constexpr int Hsz  = 2048;
constexpr int Tenc = 65;   // k+2 encoder steps
constexpr int Tdec = 64;   // k+1 decoder steps

typedef _Float16 half8 __attribute__((ext_vector_type(8)));
typedef float    f32x4 __attribute__((ext_vector_type(4)));
typedef unsigned int uint;
typedef unsigned short ushort;

// ---- packed split-fp16 pair: lo = f16(v), hi = f16((v - lo) * 4096) ----
__device__ inline uint pack_split(float v) {
    _Float16 a0 = (_Float16)v;
    float r = (v - (float)a0) * 4096.f;
    _Float16 a1 = (_Float16)r;
    return ((uint)__builtin_bit_cast(ushort, a1) << 16) | __builtin_bit_cast(ushort, a0);
}

struct U8 { uint4 a, b; };
__device__ inline U8 ld8(const uint* __restrict__ p) {
    U8 r; r.a = *(const uint4*)p; r.b = *(const uint4*)(p + 4); return r;
}

// 8 fp32 -> (lo8, hi8) split halves (fallback path)
__device__ inline void split8(const U8& v, half8& lo, half8& hi) {
    union { uint4 u; float f[4]; } A, B;
    A.u = v.a; B.u = v.b;
    float x[8] = {A.f[0], A.f[1], A.f[2], A.f[3], B.f[0], B.f[1], B.f[2], B.f[3]};
#pragma unroll
    for (int e = 0; e < 8; ++e) {
        _Float16 a0 = (_Float16)x[e];
        float r = (x[e] - (float)a0) * 4096.f;
        lo[e] = a0; hi[e] = (_Float16)r;
    }
}

// 8 packed uint32 -> (lo8, hi8) via byte-perm
__device__ inline void unpack8(const U8& v, half8& lo, half8& hi) {
    union { uint u[4]; half8 h; } L, H;
    uint w[8] = {v.a.x, v.a.y, v.a.z, v.a.w, v.b.x, v.b.y, v.b.z, v.b.w};
#pragma unroll
    for (int q = 0; q < 4; ++q) {
        L.u[q] = __builtin_amdgcn_perm(w[2*q+1], w[2*q], 0x05040100u);
        H.u[q] = __builtin_amdgcn_perm(w[2*q+1], w[2*q], 0x07060302u);
    }
    lo = L.h; hi = H.h;
}

// async global(16B) -> LDS, per-lane global src, wave-uniform LDS base
__device__ __forceinline__ void gll16(const uint* g, uint* l) {
    __builtin_amdgcn_global_load_lds(
        (const __attribute__((address_space(1))) void*)(uintptr_t)g,
        (__attribute__((address_space(3))) void*)(unsigned int)(uintptr_t)l,
        16, 0, 0);
}

// ===========================================================================
// Split-K packed split-f16 GEMM. Tile 128x128, 4 waves (2x2), wave-tile
// 64x64, BK=64, depth-2 LDS ping-pong (128 KiB), global_load_lds staging.
// P[ks] = A1*B1^T (K1 rounds) + A2*B2^T (K2 rounds)  -- raw f32 partials.
// All inputs packed uint32 (lo f16 | hi f16<<16), row-major [rows][K].
// LDS row = 64 uints (256B = 16x16B units); unit u stored at
// (u&8)|((u&7)^(row&7)); inverse swizzle applied to the GLOBAL source
// address (global_load_lds dest must stay linear).
// ===========================================================================
__global__ __launch_bounds__(256, 1) void gemm_ks(
    const uint* __restrict__ A1, int K1, const uint* __restrict__ B1,
    const uint* __restrict__ A2, int K2, const uint* __restrict__ B2,
    float* __restrict__ P, int M, int N, int GM, int GN, int KS)
{
    __shared__ uint ldsA[2 * 8192];   // 2 x 128 rows x 64 uints = 64 KiB
    __shared__ uint ldsB[2 * 8192];   // 64 KiB

    const int tid  = threadIdx.x;
    const int wid  = tid >> 6, lane = tid & 63;
    const int wr   = wid >> 1, wc = wid & 1;
    const int kq   = lane >> 4, lr = lane & 15;

    // ---- XCD-stable block decode: n-strip pinned to an XCD ----
    const int L = blockIdx.x, xcd = L & 7, g = L >> 3;
    int n_b, m_b, ks;
    const int spx = GN >> 3;
    if (spx > 0) {
        n_b = xcd * spx + (g % spx);
        int r = g / spx; m_b = r % GM; ks = r / GM;
    } else {
        const int xpn = 8 / GN;
        n_b = xcd / xpn;
        int r = g * xpn + (xcd % xpn); m_b = r % GM; ks = r / GM;
    }
    const int m0 = m_b * 128, n0 = n_b * 128;

    // ---- staging source offsets (uint elements), 8 issues each for A,B ----
    int offA1[8], offA2[8], offB1[8], offB2[8];
#pragma unroll
    for (int q = 0; q < 8; ++q) {
        int U = q * 256 + tid, row = U >> 4, us = U & 15;
        int u = (us & 8) | ((us & 7) ^ (row & 7));   // inverse read-swizzle
        offA1[q] = (m0 + row) * K1 + u * 4;
        offA2[q] = (m0 + row) * K2 + u * 4;
        offB1[q] = (n0 + row) * K1 + u * 4;
        offB2[q] = (n0 + row) * K2 + u * 4;
    }
    const int ldsbase = wid * 256;     // wave-uniform (uints); +lane*16B implicit

    const int R1 = K1 / 64;
    const int R  = (K1 + K2) / 64;
    const int nr = R / KS;
    const int r0 = ks * nr;

    auto STAGE = [&](int r, int bi) {
        uint* Ab = ldsA + bi * 8192;
        uint* Bb = ldsB + bi * 8192;
        const bool ph1 = r < R1;
        const int kl = (ph1 ? r : r - R1) * 64;
        const uint* As = ph1 ? A1 : A2;
        const uint* Bs = ph1 ? B1 : B2;
#pragma unroll
        for (int q = 0; q < 8; ++q)
            gll16(As + (ph1 ? offA1[q] : offA2[q]) + kl, Ab + q * 1024 + ldsbase);
#pragma unroll
        for (int q = 0; q < 8; ++q)
            gll16(Bs + (ph1 ? offB1[q] : offB2[q]) + kl, Bb + q * 1024 + ldsbase);
    };

    f32x4 acc0[4][4] = {}; f32x4 acc1[4][4] = {};

    auto FRAG = [&](const uint* buf, int row, int hh, half8& lo, half8& hi) {
        const int s = row & 7, b = row * 16 + hh * 8;
        U8 v;
        v.a = *(const uint4*)(buf + (b + ((2 * kq)     ^ s)) * 4);
        v.b = *(const uint4*)(buf + (b + ((2 * kq + 1) ^ s)) * 4);
        unpack8(v, lo, hi);
    };

    auto COMPUTE = [&](int bi) {
        const uint* Ab = ldsA + bi * 8192;
        const uint* Bb = ldsB + bi * 8192;
#pragma unroll
        for (int hh = 0; hh < 2; ++hh) {
            half8 a0[4], a1[4];
#pragma unroll
            for (int i = 0; i < 4; ++i) FRAG(Ab, wr * 64 + i * 16 + lr, hh, a0[i], a1[i]);
#pragma unroll
            for (int j = 0; j < 4; ++j) {
                half8 b0, b1;
                FRAG(Bb, wc * 64 + j * 16 + lr, hh, b0, b1);
#pragma unroll
                for (int i = 0; i < 4; ++i) {
                    acc0[i][j] = __builtin_amdgcn_mfma_f32_16x16x32_f16(a0[i], b0, acc0[i][j], 0, 0, 0);
                    acc1[i][j] = __builtin_amdgcn_mfma_f32_16x16x32_f16(a1[i], b0, acc1[i][j], 0, 0, 0);
                    acc1[i][j] = __builtin_amdgcn_mfma_f32_16x16x32_f16(a0[i], b1, acc1[i][j], 0, 0, 0);
                }
            }
        }
    };

    // ---- prologue: stage rounds r0, r0+1 into buffers 0,1 ----
    STAGE(r0, 0);
    if (nr > 1) STAGE(r0 + 1, 1);
    __builtin_amdgcn_sched_barrier(0);
    if (nr > 1) asm volatile("s_waitcnt vmcnt(16)" ::: "memory");
    else        asm volatile("s_waitcnt vmcnt(0)"  ::: "memory");
    __builtin_amdgcn_s_barrier();
    __builtin_amdgcn_sched_barrier(0);

    // ---- main loop: 2-phase, ping-pong ----
    int bi = 0;
    for (int t = 0; t < nr; ++t) {
        COMPUTE(bi);
        if (t + 1 < nr) {
            __builtin_amdgcn_sched_barrier(0);
            __builtin_amdgcn_s_barrier();          // all waves done reading bi
            __builtin_amdgcn_sched_barrier(0);
            if (t + 2 < nr) {
                STAGE(r0 + t + 2, bi);
                __builtin_amdgcn_sched_barrier(0);
                asm volatile("s_waitcnt vmcnt(16)" ::: "memory");  // drain t+1
            } else {
                asm volatile("s_waitcnt vmcnt(0)" ::: "memory");
            }
            __builtin_amdgcn_s_barrier();          // t+1 data visible to all
            __builtin_amdgcn_sched_barrier(0);
            bi ^= 1;
        }
    }

    // ---- epilogue: raw f32 partial ----
    float* Pk = P + (size_t)ks * M * N;
#pragma unroll
    for (int j = 0; j < 4; ++j) {
        const int n = n0 + wc * 64 + j * 16 + lr;
#pragma unroll
        for (int i = 0; i < 4; ++i) {
            const int mb = m0 + wr * 64 + i * 16 + kq * 4;
#pragma unroll
            for (int r = 0; r < 4; ++r)
                Pk[(size_t)(mb + r) * N + n] = acc0[i][j][r] + 0x1p-12f * acc1[i][j][r];
        }
    }
}

// ---------------------------------------------------------------------------
// Combine 2 partials + biases, tanh, pack-split -> next h (packed uint)
// ---------------------------------------------------------------------------
__global__ __launch_bounds__(256) void combine_h(
    const float* __restrict__ P, const float* __restrict__ b1,
    const float* __restrict__ b2, uint* __restrict__ hout, int MN, int N)
{
    const int i0 = (blockIdx.x * 256 + threadIdx.x) * 4;
    if (i0 >= MN) return;
    float4 p0 = *(const float4*)(P + i0);
    float4 p1 = *(const float4*)(P + MN + i0);
    const int n = i0 & (N - 1);
    uint4 o;
    o.x = pack_split(tanhf(p0.x + p1.x + b1[n + 0] + b2[n + 0]));
    o.y = pack_split(tanhf(p0.y + p1.y + b1[n + 1] + b2[n + 1]));
    o.z = pack_split(tanhf(p0.z + p1.z + b1[n + 2] + b2[n + 2]));
    o.w = pack_split(tanhf(p0.w + p1.w + b1[n + 3] + b2[n + 3]));
    *(uint4*)(hout + i0) = o;
}

// ===========================================================================
// FALLBACK PATH (reg-staged; handles fp32 B when ws tiny)
// ===========================================================================
#define SWZ(row, kk) (((row) * 4 + ((kk) ^ (((row) >> 1) & 3))) * 8)

template<int BM, int BN, int WR, int WC, int MP, int NP, bool TANH, bool PACKOUT>
__global__ __launch_bounds__(WR*WC*64) void gemm_sp(
    const float* __restrict__ A1, int K1, const void* __restrict__ B1,
    const uint*  __restrict__ A2, int K2, const void* __restrict__ B2,
    int b_f32,
    const float* __restrict__ bias1, const float* __restrict__ bias2,
    void* __restrict__ C, int M, int N)
{
    constexpr int NT  = WR * WC * 64;
    constexpr int AUP = BM * 4 / NT;
    constexpr int BUP = BN * 4 / NT;

    __shared__ __align__(16) _Float16 As0[BM*32], As1[BM*32];
    __shared__ __align__(16) _Float16 Bs0[BN*32], Bs1[BN*32];

    const int tid  = threadIdx.x;
    const int wid  = tid >> 6, lane = tid & 63;
    const int wrow = wid / WC, wcol = wid % WC;
    const int kq   = lane >> 4, lr = lane & 15;
    const int m0   = blockIdx.y * BM;
    const int n0   = blockIdx.x * BN;

    int aum[AUP], auk[AUP]; _Float16 *aw0[AUP], *aw1[AUP];
#pragma unroll
    for (int p = 0; p < AUP; ++p) {
        int u = tid + p * NT; aum[p] = u >> 2; auk[p] = u & 3;
        int o = SWZ(aum[p], auk[p]); aw0[p] = As0 + o; aw1[p] = As1 + o;
    }
    int bun[BUP], buk[BUP]; _Float16 *bw0[BUP], *bw1[BUP];
#pragma unroll
    for (int p = 0; p < BUP; ++p) {
        int u = tid + p * NT; bun[p] = u >> 2; buk[p] = u & 3;
        int o = SWZ(bun[p], buk[p]); bw0[p] = Bs0 + o; bw1[p] = Bs1 + o;
    }
    int aoff[MP], boff[NP];
#pragma unroll
    for (int i = 0; i < MP; ++i) { int m = wrow*(MP*16) + i*16 + lr; aoff[i] = SWZ(m, kq); }
#pragma unroll
    for (int j = 0; j < NP; ++j) { int n = wcol*(NP*16) + j*16 + lr; boff[j] = SWZ(n, kq); }

    f32x4 acc0[MP][NP] = {}; f32x4 acc1[MP][NP] = {};

    const int R = (K1 + K2) / 32;

    auto issue = [&](int rd, U8* aR, U8* bR) {
        const bool ph1 = (rd * 32) < K1;
        const int  kl  = ph1 ? rd * 32 : rd * 32 - K1;
        const int  Ka  = ph1 ? K1 : K2;
        const uint* Ap = ph1 ? (const uint*)A1 : A2;
        const uint* Bp = (const uint*)(ph1 ? B1 : B2);
#pragma unroll
        for (int p = 0; p < AUP; ++p)
            aR[p] = ld8(Ap + (size_t)(m0 + aum[p]) * Ka + kl + auk[p] * 8);
#pragma unroll
        for (int p = 0; p < BUP; ++p)
            bR[p] = ld8(Bp + (size_t)(n0 + bun[p]) * Ka + kl + buk[p] * 8);
    };

    auto stage = [&](U8* aR, U8* bR, bool aF32) {
#pragma unroll
        for (int p = 0; p < AUP; ++p) {
            half8 lo, hi;
            if (aF32) split8(aR[p], lo, hi); else unpack8(aR[p], lo, hi);
            *(half8*)aw0[p] = lo; *(half8*)aw1[p] = hi;
        }
#pragma unroll
        for (int p = 0; p < BUP; ++p) {
            half8 lo, hi;
            if (b_f32) split8(bR[p], lo, hi); else unpack8(bR[p], lo, hi);
            *(half8*)bw0[p] = lo; *(half8*)bw1[p] = hi;
        }
    };

    auto compute = [&]() {
        half8 a0[MP], a1[MP], b0[NP], b1[NP];
#pragma unroll
        for (int i = 0; i < MP; ++i) {
            a0[i] = *(const half8*)(As0 + aoff[i]);
            a1[i] = *(const half8*)(As1 + aoff[i]);
        }
#pragma unroll
        for (int j = 0; j < NP; ++j) {
            b0[j] = *(const half8*)(Bs0 + boff[j]);
            b1[j] = *(const half8*)(Bs1 + boff[j]);
        }
#pragma unroll
        for (int i = 0; i < MP; ++i)
#pragma unroll
            for (int j = 0; j < NP; ++j) {
                acc0[i][j] = __builtin_amdgcn_mfma_f32_16x16x32_f16(a0[i], b0[j], acc0[i][j], 0, 0, 0);
                acc1[i][j] = __builtin_amdgcn_mfma_f32_16x16x32_f16(a1[i], b0[j], acc1[i][j], 0, 0, 0);
                acc1[i][j] = __builtin_amdgcn_mfma_f32_16x16x32_f16(a0[i], b1[j], acc1[i][j], 0, 0, 0);
            }
    };

    U8 aA[AUP], bA[BUP], aB[AUP], bB[BUP];
    issue(0, aA, bA);
    for (int rd = 0; rd < R; rd += 2) {
        if (rd + 1 < R) issue(rd + 1, aB, bB);
        stage(aA, bA, (rd * 32) < K1);
        __syncthreads();
        compute();
        __syncthreads();
        if (rd + 1 < R) {
            if (rd + 2 < R) issue(rd + 2, aA, bA);
            stage(aB, bB, ((rd + 1) * 32) < K1);
            __syncthreads();
            compute();
            __syncthreads();
        }
    }

#pragma unroll
    for (int j = 0; j < NP; ++j) {
        const int n = n0 + wcol*(NP*16) + j*16 + lr;
        float bb = bias1 ? bias1[n] : 0.f;
        if (bias2) bb += bias2[n];
#pragma unroll
        for (int i = 0; i < MP; ++i) {
            const int mb = m0 + wrow*(MP*16) + i*16 + kq*4;
#pragma unroll
            for (int r = 0; r < 4; ++r) {
                float val = acc0[i][j][r] + 0x1p-12f * acc1[i][j][r] + bb;
                if (TANH) val = tanhf(val);
                if (PACKOUT)
                    ((uint*)C)[(size_t)(mb + r) * N + n] = pack_split(val);
                else
                    ((float*)C)[(size_t)(mb + r) * N + n] = val;
            }
        }
    }
}

// ---------------------------------------------------------------------------
__global__ __launch_bounds__(256) void split_pack_k(
    const float* __restrict__ s, uint* __restrict__ d, int n)
{
    for (int i = blockIdx.x * 256 + threadIdx.x; i < n; i += gridDim.x * 256)
        d[i] = pack_split(s[i]);
}

// ---------------------------------------------------------------------------
// log_softmax over Isz=512 (sum of NPART partials + rob), argmax==2,
// fused done-latch: rows with done==1 become one-hot begin.
// ---------------------------------------------------------------------------
template<int NPART>
__global__ __launch_bounds__(256) void logsoftmax_done(
    const float* __restrict__ parts, const float* __restrict__ rob,
    float* __restrict__ done, float* __restrict__ out)
{
    const int b   = blockIdx.x;
    const int tid = threadIdx.x;
    const size_t S = (size_t)Bsz * Isz;
    const float* row = parts + (size_t)b * Isz;

    float v0, v1;
    if (NPART == 1) { v0 = row[tid]; v1 = row[tid + 256]; }
    else {
        v0 = rob[tid]; v1 = rob[tid + 256];
#pragma unroll
        for (int p = 0; p < NPART; ++p) { v0 += row[p*S + tid]; v1 += row[p*S + tid + 256]; }
    }

    float mv; int mi;
    if (v0 >= v1) { mv = v0; mi = tid; } else { mv = v1; mi = tid + 256; }
#pragma unroll
    for (int off = 32; off; off >>= 1) {
        float ov = __shfl_xor(mv, off);
        int   oi = __shfl_xor(mi, off);
        if (ov > mv || (ov == mv && oi < mi)) { mv = ov; mi = oi; }
    }
    __shared__ float smv[4];
    __shared__ int   smi[4];
    __shared__ float sdone;
    const int wid = tid >> 6, lane = tid & 63;
    if (lane == 0) { smv[wid] = mv; smi[wid] = mi; }
    __syncthreads();
    if (tid == 0) {
        for (int w = 1; w < 4; ++w)
            if (smv[w] > smv[0] || (smv[w] == smv[0] && smi[w] < smi[0])) {
                smv[0] = smv[w]; smi[0] = smi[w];
            }
        float z = (smi[0] == 2) ? 1.f : 0.f;
        float dn = fmaxf(done[b], z);
        done[b] = dn;
        sdone = dn;
    }
    __syncthreads();
    mv = smv[0];

    float s = expf(v0 - mv) + expf(v1 - mv);
#pragma unroll
    for (int off = 32; off; off >>= 1) s += __shfl_xor(s, off);
    __shared__ float ssum[4];
    if (lane == 0) ssum[wid] = s;
    __syncthreads();
    if (tid == 0) ssum[0] = ssum[0] + ssum[1] + ssum[2] + ssum[3];
    __syncthreads();
    const float ls = logf(ssum[0]);

    float* orow = out + (size_t)b * Isz;
    if (sdone > 0.5f) {
        orow[tid]       = (tid == 0) ? 1.f : 0.f;
        orow[tid + 256] = 0.f;
    } else {
        orow[tid]       = v0 - mv - ls;
        orow[tid + 256] = v1 - mv - ls;
    }
}

// ---------------------------------------------------------------------------
extern "C" void kernel_launch(void* const* d_in, const int* in_sizes, int n_in,
                              void* d_out, int out_size, void* d_ws, size_t ws_size,
                              hipStream_t stream)
{
    const float* x    = (const float*)d_in[0];
    const float* eWih = (const float*)d_in[1];
    const float* eWhh = (const float*)d_in[2];
    const float* ebih = (const float*)d_in[3];
    const float* ebhh = (const float*)d_in[4];
    const float* dWhh = (const float*)d_in[6];
    const float* dbih = (const float*)d_in[7];
    const float* dbhh = (const float*)d_in[8];
    const float* roW  = (const float*)d_in[9];
    const float* rob  = (const float*)d_in[10];
    float* out = (float*)d_out;

    const size_t sz_eWih = (size_t)Hsz * Isz * 4;            //  4 MB
    const size_t sz_eWhh = (size_t)Hsz * Hsz * 4;            // 16 MB
    const size_t sz_roW  = (size_t)Isz * Hsz * 4;            //  4 MB
    const size_t sz_h    = (size_t)Bsz * Hsz * 4;            //  8 MB packed
    const size_t sz_part = (size_t)8 * Bsz * Isz * 4;        // 16 MB (8 ro-parts / 2 h-parts)
    const size_t sz_done = (size_t)Bsz * 4;
    const size_t sz_px   = (size_t)Tenc * Bsz * Isz * 4;     // 136 MB
    const size_t sz_slot = (size_t)Bsz * Isz * 4;            //  2 MB

    const size_t base_need = sz_eWih + 2*sz_eWhh + sz_roW + 2*sz_h + sz_part + sz_done;
    const int mode = (ws_size >= base_need + sz_px) ? 2
                   : (ws_size >= base_need + sz_slot) ? 1 : 0;

    char* ws = (char*)d_ws;

    if (mode >= 1) {
        size_t off = 0;
        uint* pWih  = (uint*)(ws + off); off += sz_eWih;
        uint* pWhh  = (uint*)(ws + off); off += sz_eWhh;
        uint* pdWhh = (uint*)(ws + off); off += sz_eWhh;
        uint* proW  = (uint*)(ws + off); off += sz_roW;
        uint* hA    = (uint*)(ws + off); off += sz_h;
        uint* hB    = (uint*)(ws + off); off += sz_h;
        float* parts= (float*)(ws + off); off += sz_part;
        float* done = (float*)(ws + off); off += sz_done;
        uint* px    = (uint*)(ws + off);   // mode2: 65 steps; mode1: 1-step slot

        split_pack_k<<<dim3(1024), dim3(256), 0, stream>>>(eWih, pWih,  Hsz*Isz);
        split_pack_k<<<dim3(2048), dim3(256), 0, stream>>>(eWhh, pWhh,  Hsz*Hsz);
        split_pack_k<<<dim3(2048), dim3(256), 0, stream>>>(dWhh, pdWhh, Hsz*Hsz);
        split_pack_k<<<dim3(1024), dim3(256), 0, stream>>>(roW,  proW,  Isz*Hsz);
        if (mode == 2)
            split_pack_k<<<dim3(2048), dim3(256), 0, stream>>>(x, px, Tenc*Bsz*Isz);

        hipMemsetAsync(hA, 0, sz_h, stream);
        hipMemsetAsync(done, 0, sz_done, stream);

        const int MNh = Bsz * Hsz;
        uint* h[2] = { hA, hB };
        int cur = 0;
        // ---- encoder: K = 512 + 2048, KS=2 -> 256 blocks ----
        for (int t = 0; t < Tenc; ++t) {
            const uint* xs;
            if (mode == 2) xs = px + (size_t)t * Bsz * Isz;
            else {
                split_pack_k<<<dim3(512), dim3(256), 0, stream>>>(
                    x + (size_t)t * Bsz * Isz, px, Bsz*Isz);
                xs = px;
            }
            gemm_ks<<<dim3(256), dim3(256), 0, stream>>>(
                xs, Isz, pWih, h[cur], Hsz, pWhh,
                parts, Bsz, Hsz, 8, 16, 2);
            combine_h<<<dim3(MNh / 1024), dim3(256), 0, stream>>>(
                parts, ebih, ebhh, h[cur ^ 1], MNh, Hsz);
            cur ^= 1;
        }
        // ---- decoder ----
        for (int t = 0; t < Tdec; ++t) {
            gemm_ks<<<dim3(256), dim3(256), 0, stream>>>(
                nullptr, 0, nullptr, h[cur], Hsz, pdWhh,
                parts, Bsz, Hsz, 8, 16, 2);
            combine_h<<<dim3(MNh / 1024), dim3(256), 0, stream>>>(
                parts, dbih, dbhh, h[cur ^ 1], MNh, Hsz);
            cur ^= 1;
            gemm_ks<<<dim3(256), dim3(256), 0, stream>>>(
                nullptr, 0, nullptr, h[cur], Hsz, proW,
                parts, Bsz, Isz, 8, 4, 8);
            logsoftmax_done<8><<<dim3(Bsz), dim3(256), 0, stream>>>(
                parts, rob, done, out + (size_t)t * Bsz * Isz);
        }
        return;
    }

    // ================= fallback path =================
    {
        const size_t sz_lg = (size_t)Bsz * Isz * 4;
        size_t off = 0;
        uint*  hA     = (uint*)(ws + off); off += sz_h;
        uint*  hB     = (uint*)(ws + off); off += sz_h;
        float* logits = (float*)(ws + off); off += sz_lg;
        float* done   = (float*)(ws + off);

        hipMemsetAsync(hA, 0, sz_h, stream);
        hipMemsetAsync(done, 0, sz_done, stream);

        uint* h[2] = { hA, hB };
        const dim3 blk(256);
        const dim3 grid_h(Hsz / 128, Bsz / 64);
        const dim3 grid_ro(Isz / 64, Bsz / 64);

        int cur = 0;
        for (int t = 0; t < Tenc; ++t) {
            gemm_sp<64, 128, 2, 2, 2, 4, true, true><<<grid_h, blk, 0, stream>>>(
                x + (size_t)t * Bsz * Isz, Isz, eWih,
                h[cur], Hsz, eWhh, 1,
                ebih, ebhh, h[cur ^ 1], Bsz, Hsz);
            cur ^= 1;
        }
        for (int t = 0; t < Tdec; ++t) {
            gemm_sp<64, 128, 2, 2, 2, 4, true, true><<<grid_h, blk, 0, stream>>>(
                nullptr, 0, nullptr, h[cur], Hsz, dWhh, 1,
                dbih, dbhh, h[cur ^ 1], Bsz, Hsz);
            cur ^= 1;
            gemm_sp<64, 64, 2, 2, 2, 2, false, false><<<grid_ro, blk, 0, stream>>>(
                nullptr, 0, nullptr, h[cur], Hsz, roW, 1,
                rob, nullptr, logits, Bsz, Isz);
            logsoftmax_done<1><<<dim3(Bsz), dim3(256), 0, stream>>>(
                logits, rob, done, out + (size_t)t * Bsz * Isz);
        }
    }
}